// Round 14
// baseline (205.588 us; speedup 1.0000x reference)
//
#include <hip/hip_runtime.h>

// BaseAttention: B=2 H=16 S=2048 D=64, fp32 in/out.
// Round 18: SELF-STAGING main kernel -- eliminate prep_kv + its dispatch.
//   r17 post-mortem: 5 passing structures all 76-77us; every counter lever
//   (conflicts->0, FETCH-24%, VALU->MFMA shift, occupancy 2x, swizzle) moved
//   its counter but NOT time. Meanwhile total-attn ~= 90us constant across
//   all rounds -- the prep/dispatch pipeline is now the dominant cost and has
//   never been attacked directly.
//   This round: fold K/V conversion into attn_fwd from raw fp32 (L3-resident,
//   64MB): attn_fwd_self's staging code (r4-validated: pitch-72 bf16 K [key][d],
//   swizzled f16 V transpose) + r13's consumer (passed at 77us on these exact
//   layouts). Plain C++ loads only -- no asm, no DMA, no counted vmcnt (the
//   r15/r16 bug class is structurally impossible; compiler auto-waitcnts).
//   ONE __syncthreads/iter: iter kt reads buf[p], stages tile kt+1 into
//   buf[p^1] (loads at top, convert+ds_write after compute; locals never
//   cross a barrier => no r12 spill). Only prep_mask (tiny, r12-validated)
//   survives as a prep. Kept: XCD swizzle, kh-split 4-wave blocks, Q
//   pre-scaled 0.125*log2e, mask AND-words, P packed f16 pkrtz, ones-A MFMA
//   l, setprio, PV mfma_32x32x16_f16, LDS-alias epilogue.
//   Decisive read: total ~105-120 => residue was prep/dispatch (win);
//   total >=160 => fixed harness floor (redirects the session).

#define S_LEN 2048
#define D_DIM 64
#define N_KT 32
#define NBH 32
#define LDK 72
#define LDV 72
#define K_SHORTS (64 * LDK)              // 4608 shorts = 9216 B per tile

typedef __attribute__((ext_vector_type(8))) short bf16x8;
typedef __attribute__((ext_vector_type(16))) float f32x16;
typedef __attribute__((ext_vector_type(2))) __fp16 fp16x2;
typedef unsigned int u32;

#define C1 0.180336880111121f    // 0.125 * log2(e)
#define CM (-14426.9504088896f)  // -10000 * log2(e)  (fallback kernel only)

static __device__ __forceinline__ unsigned short f2bf(float f) {
  union { float f; unsigned u; } x; x.f = f;
  return (unsigned short)((x.u + 0x8000u) >> 16);
}
static __device__ __forceinline__ unsigned packbf(float lo, float hi) {
  union { float f; unsigned u; } a, b; a.f = lo; b.f = hi;
  return ((a.u + 0x8000u) >> 16) | ((b.u + 0x8000u) & 0xffff0000u);
}
static __device__ __forceinline__ f32x16 zero16() {
  f32x16 z;
#pragma unroll
  for (int i = 0; i < 16; ++i) z[i] = 0.f;
  return z;
}
static __device__ __forceinline__ unsigned pkh(float lo, float hi) {
  union { fp16x2 h; unsigned u; } x;
  x.h = __builtin_amdgcn_cvt_pkrtz(lo, hi);
  return x.u;
}

// ---- pre-pass: mask -> u32 AND-words (r12-validated, standalone) ----
// word p=kb*8+g*2+h of (row,hl,kt) covers keys j=32kb+8g+4hl+2h+{0,1};
// mask==0 -> keep (0xFFFF).
__global__ __launch_bounds__(256) void prep_mask(
    const int* __restrict__ mask, u32* __restrict__ mw) {
  const int gt = blockIdx.x * 256 + threadIdx.x;  // 524288 total
  const int q4 = gt & 3;
  const int kt = (gt >> 2) & 31;
  const int hl = (gt >> 7) & 1;
  const int row = gt >> 8;
  const int j0 = kt * 64 + 32 * (q4 >> 1) + 16 * (q4 & 1) + 4 * hl;
  const int* mr = mask + (size_t)row * S_LEN;
  const int4 a = *(const int4*)(mr + j0);
  const int4 b = *(const int4*)(mr + j0 + 8);
  uint4 w;
  w.x = (a.x == 0 ? 0x0000FFFFu : 0u) | (a.y == 0 ? 0xFFFF0000u : 0u);
  w.y = (a.z == 0 ? 0x0000FFFFu : 0u) | (a.w == 0 ? 0xFFFF0000u : 0u);
  w.z = (b.x == 0 ? 0x0000FFFFu : 0u) | (b.y == 0 ? 0xFFFF0000u : 0u);
  w.w = (b.z == 0 ? 0x0000FFFFu : 0u) | (b.w == 0 ? 0xFFFF0000u : 0u);
  *(uint4*)&mw[((size_t)(row * 2 + hl) * N_KT + kt) * 16 + q4 * 4] = w;
}

// ---- main: self-staging flash attention, 1 barrier/iter ----
__global__ __launch_bounds__(256, 4) void attn_fwd(
    const float* __restrict__ q, const float* __restrict__ k,
    const float* __restrict__ v, const u32* __restrict__ mw,
    float* __restrict__ out) {
  // XCD swizzle (r17-validated): XCD x hosts bh in [4x,4x+4) x all qt.
  const int lin = blockIdx.x + 32 * blockIdx.y;
  const int xcd = lin & 7;
  const int wk = lin >> 3;
  const int qt = wk & 31;
  const int bh = xcd * 4 + (wk >> 5);
  const size_t hoff = (size_t)bh * (S_LEN * D_DIM);

  __shared__ unsigned short Ks[2][K_SHORTS];   // bf16 [key][d] pitch 72
  __shared__ unsigned short Vt[2][K_SHORTS];   // f16 swizzled transpose

  const int t = threadIdx.x;
  const int wave = t >> 6;
  const int lane = t & 63;
  const int col = lane & 31;
  const int hl = lane >> 5;
  const int sw = col >> 2;
  const int qh = wave >> 1;  // q half
  const int kh = wave & 1;   // key half of each tile
  const int qg = qt * 64 + qh * 32 + col;

  // Q^T B-fragments, PRE-SCALED by C1
  bf16x8 bQ[4];
  {
    const float* qrow = q + hoff + (size_t)qg * D_DIM;
#pragma unroll
    for (int ks = 0; ks < 4; ++ks) {
      const float4 x0 = *(const float4*)(qrow + ks * 16 + hl * 8);
      const float4 x1 = *(const float4*)(qrow + ks * 16 + hl * 8 + 4);
      union { bf16x8 v; unsigned d[4]; } u;
      u.d[0] = packbf(x0.x * C1, x0.y * C1);
      u.d[1] = packbf(x0.z * C1, x0.w * C1);
      u.d[2] = packbf(x1.x * C1, x1.y * C1);
      u.d[3] = packbf(x1.z * C1, x1.w * C1);
      bQ[ks] = u.v;
    }
  }

  // ones A-fragment (f16 1.0) for the l row-sum MFMA (r8/r17-validated)
  bf16x8 onesA;
  {
    union { bf16x8 v; unsigned d[4]; } u;
    u.d[0] = u.d[1] = u.d[2] = u.d[3] = 0x3C003C00u;
    onesA = u.v;
  }

  f32x16 oT0 = zero16(), oT1 = zero16(), oL = zero16();
  const uint4* mrow = (const uint4*)(mw + (size_t)(qg * 2 + hl) * N_KT * 16);
  const float* kbase = k + hoff;
  const float* vbase = v + hoff;

  // staging writer (attn_fwd_self / r4-validated layout math)
  auto stage_write = [&](int p, const float4* kx, const float4* vx) {
#pragma unroll
    for (int j = 0; j < 4; ++j) {
      const int i = t + j * 256;
      const int row = i >> 4, c4 = i & 15;  // row = key, c4 = d-group
      ushort4 w;
      w.x = f2bf(kx[j].x); w.y = f2bf(kx[j].y);
      w.z = f2bf(kx[j].z); w.w = f2bf(kx[j].w);
      *(ushort4*)&Ks[p][row * LDK + c4 * 4] = w;
      const int swc = 8 * (((row >> 3) + c4) & 7) + (row & 7);
      const unsigned p01 = pkh(vx[j].x, vx[j].y);
      const unsigned p23 = pkh(vx[j].z, vx[j].w);
      Vt[p][(4 * c4 + 0) * LDV + swc] = (unsigned short)(p01 & 0xffff);
      Vt[p][(4 * c4 + 1) * LDV + swc] = (unsigned short)(p01 >> 16);
      Vt[p][(4 * c4 + 2) * LDV + swc] = (unsigned short)(p23 & 0xffff);
      Vt[p][(4 * c4 + 3) * LDV + swc] = (unsigned short)(p23 >> 16);
    }
  };

  // prologue: stage tile 0 into buf 0
  {
    const float4* kg = (const float4*)kbase;
    const float4* vg = (const float4*)vbase;
    float4 kx[4], vx[4];
#pragma unroll
    for (int j = 0; j < 4; ++j) { kx[j] = kg[t + j * 256]; vx[j] = vg[t + j * 256]; }
    stage_write(0, kx, vx);
  }
  __syncthreads();

  for (int kt = 0; kt < N_KT; ++kt) {
    const int p = kt & 1;

    // top of iter: issue next-tile loads + this-tile mask loads (plain C++,
    // compiler schedules early / waitcnts at use; no barrier before use)
    float4 kx[4], vx[4];
    if (kt + 1 < N_KT) {
      const float4* kg = (const float4*)(kbase + (size_t)(kt + 1) * 64 * D_DIM);
      const float4* vg = (const float4*)(vbase + (size_t)(kt + 1) * 64 * D_DIM);
#pragma unroll
      for (int j = 0; j < 4; ++j) { kx[j] = kg[t + j * 256]; vx[j] = vg[t + j * 256]; }
    }
    const uint4 mq0 = mrow[kt * 4 + kh * 2 + 0];
    const uint4 mq1 = mrow[kt * 4 + kh * 2 + 1];
    const u32 mwv[8] = {mq0.x, mq0.y, mq0.z, mq0.w,
                        mq1.x, mq1.y, mq1.z, mq1.w};

    const unsigned short* Ksb = Ks[p];
    const unsigned short* Vtb = Vt[p];

    // S^T = K Q^T : this wave's 32-key half x K=64 (r13-validated consumer)
    f32x16 sT = zero16();
    __builtin_amdgcn_s_setprio(1);
#pragma unroll
    for (int ks = 0; ks < 4; ++ks) {
      const bf16x8 aK =
          *(const bf16x8*)&Ksb[(kh * 32 + col) * LDK + ks * 16 + hl * 8];
      sT = __builtin_amdgcn_mfma_f32_32x32x16_bf16(aK, bQ[ks], sT, 0, 0, 0);
    }
    __builtin_amdgcn_s_setprio(0);

    // p = exp2(s), pack f16 (pkrtz), mask with AND-words
    unsigned pw[8];
#pragma unroll
    for (int g2 = 0; g2 < 4; ++g2) {
      const float e0 = __builtin_amdgcn_exp2f(sT[g2 * 4 + 0]);
      const float e1 = __builtin_amdgcn_exp2f(sT[g2 * 4 + 1]);
      const float e2 = __builtin_amdgcn_exp2f(sT[g2 * 4 + 2]);
      const float e3 = __builtin_amdgcn_exp2f(sT[g2 * 4 + 3]);
      pw[g2 * 2 + 0] = pkh(e0, e1) & mwv[g2 * 2 + 0];
      pw[g2 * 2 + 1] = pkh(e2, e3) & mwv[g2 * 2 + 1];
    }

    // O^T += Vt * P^T ; l += ones * P^T (r13-validated cpr rotation)
    __builtin_amdgcn_s_setprio(1);
#pragma unroll
    for (int ks2 = 0; ks2 < 2; ++ks2) {
      const unsigned d0 = pw[4 * ks2 + 0], d1 = pw[4 * ks2 + 1];
      const unsigned d2 = pw[4 * ks2 + 2], d3 = pw[4 * ks2 + 3];
      const unsigned s0 = hl ? d0 : d2;
      const unsigned s1 = hl ? d1 : d3;
      const unsigned r0 = (unsigned)__shfl_xor((int)s0, 32);
      const unsigned r1 = (unsigned)__shfl_xor((int)s1, 32);
      union { bf16x8 v; unsigned d[4]; } pf;
      pf.d[0] = hl ? r0 : d0;
      pf.d[1] = hl ? r1 : d1;
      pf.d[2] = hl ? d2 : r0;
      pf.d[3] = hl ? d3 : r1;
      const int cpr = 8 * (((4 * kh + 2 * ks2 + hl) + sw) & 7);
      const bf16x8 aV0 = *(const bf16x8*)&Vtb[col * LDV + cpr];
      const bf16x8 aV1 = *(const bf16x8*)&Vtb[(32 + col) * LDV + cpr];
      oT0 = __builtin_amdgcn_mfma_f32_32x32x16_f16(aV0, pf.v, oT0, 0, 0, 0);
      oT1 = __builtin_amdgcn_mfma_f32_32x32x16_f16(aV1, pf.v, oT1, 0, 0, 0);
      oL = __builtin_amdgcn_mfma_f32_32x32x16_f16(onesA, pf.v, oL, 0, 0, 0);
    }
    __builtin_amdgcn_s_setprio(0);

    // stage tile kt+1 into buf[p^1] (its old contents, tile kt-1, were fully
    // consumed before the PREVIOUS barrier => write-after-read safe)
    if (kt + 1 < N_KT) stage_write(p ^ 1, kx, vx);

    __syncthreads();  // orders: my reads of buf[p] done; tile kt+1 visible
  }

  // ---- cross-wave key-half reduction via LDS alias over Ks ----
  // (18432 B >= 17408 + 256 needed)
  {
    float* xb = (float*)&Ks[0][0];
    float* lb = (float*)((char*)&Ks[0][0] + 17408);
    float* xr = xb + (size_t)(qh * 32 + col) * 68;
    if (kh) {
#pragma unroll
      for (int rg = 0; rg < 4; ++rg) {
        float4 w0, w1;
        w0.x = oT0[rg * 4 + 0]; w0.y = oT0[rg * 4 + 1];
        w0.z = oT0[rg * 4 + 2]; w0.w = oT0[rg * 4 + 3];
        w1.x = oT1[rg * 4 + 0]; w1.y = oT1[rg * 4 + 1];
        w1.z = oT1[rg * 4 + 2]; w1.w = oT1[rg * 4 + 3];
        *(float4*)(xr + 8 * rg + 4 * hl) = w0;
        *(float4*)(xr + 32 + 8 * rg + 4 * hl) = w1;
      }
      if (!hl) lb[qh * 32 + col] = oL[0];  // every C row of ones*P^T = l(q=col)
    }
    __syncthreads();
    if (!kh) {
      const float inv = 1.0f / (oL[0] + lb[qh * 32 + col]);
      float* orow = out + hoff + (size_t)qg * D_DIM;
#pragma unroll
      for (int rg = 0; rg < 4; ++rg) {
        const float4 a0 = *(const float4*)(xr + 8 * rg + 4 * hl);
        const float4 a1 = *(const float4*)(xr + 32 + 8 * rg + 4 * hl);
        float4 w0, w1;
        w0.x = (oT0[rg * 4 + 0] + a0.x) * inv;
        w0.y = (oT0[rg * 4 + 1] + a0.y) * inv;
        w0.z = (oT0[rg * 4 + 2] + a0.z) * inv;
        w0.w = (oT0[rg * 4 + 3] + a0.w) * inv;
        w1.x = (oT1[rg * 4 + 0] + a1.x) * inv;
        w1.y = (oT1[rg * 4 + 1] + a1.y) * inv;
        w1.z = (oT1[rg * 4 + 2] + a1.z) * inv;
        w1.w = (oT1[rg * 4 + 3] + a1.w) * inv;
        *(float4*)(orow + 8 * rg + 4 * hl) = w0;
        *(float4*)(orow + 32 + 8 * rg + 4 * hl) = w1;
      }
    }
  }
}

// ---- fallback (round-4 kernel, self-staging) if ws is too small ----
__global__ __launch_bounds__(256, 2) void attn_fwd_self(
    const float* __restrict__ q, const float* __restrict__ k,
    const float* __restrict__ v, const int* __restrict__ mask,
    float* __restrict__ out) {
  const int qt = blockIdx.x;
  const int bh = blockIdx.y;
  const size_t hoff = (size_t)bh * (S_LEN * D_DIM);
  __shared__ unsigned short Ks[64 * LDK];
  __shared__ unsigned short Vt[64 * LDV];
  const int t = threadIdx.x;
  const int wave = t >> 6;
  const int lane = t & 63;
  const int col = lane & 31;
  const int hl = lane >> 5;
  const int sw = col >> 2;
  const int qg = qt * 128 + wave * 32 + col;
  bf16x8 bQ[4];
  {
    const float* qrow = q + hoff + (size_t)qg * D_DIM;
#pragma unroll
    for (int ks = 0; ks < 4; ++ks) {
      const float4 x0 = *(const float4*)(qrow + ks * 16 + hl * 8);
      const float4 x1 = *(const float4*)(qrow + ks * 16 + hl * 8 + 4);
      union { bf16x8 v; unsigned d[4]; } u;
      u.d[0] = packbf(x0.x, x0.y);
      u.d[1] = packbf(x0.z, x0.w);
      u.d[2] = packbf(x1.x, x1.y);
      u.d[3] = packbf(x1.z, x1.w);
      bQ[ks] = u.v;
    }
  }
  float4 pk[4], pv[4];
  {
    const float4* kg = (const float4*)(k + hoff);
    const float4* vg = (const float4*)(v + hoff);
#pragma unroll
    for (int j = 0; j < 4; ++j) { pk[j] = kg[t + j * 256]; pv[j] = vg[t + j * 256]; }
  }
  f32x16 oT0 = zero16(), oT1 = zero16();
  float lacc = 0.f;
  const int* mrow = mask + (size_t)qg * S_LEN;
  for (int kt = 0; kt < N_KT; ++kt) {
    __syncthreads();
#pragma unroll
    for (int j = 0; j < 4; ++j) {
      const int i = t + j * 256;
      const int row = i >> 4, c4 = i & 15;
      ushort4 w;
      w.x = f2bf(pk[j].x); w.y = f2bf(pk[j].y);
      w.z = f2bf(pk[j].z); w.w = f2bf(pk[j].w);
      *(ushort4*)&Ks[row * LDK + c4 * 4] = w;
      const int swc = 8 * (((row >> 3) + c4) & 7) + (row & 7);
      Vt[(4 * c4 + 0) * LDV + swc] = f2bf(pv[j].x);
      Vt[(4 * c4 + 1) * LDV + swc] = f2bf(pv[j].y);
      Vt[(4 * c4 + 2) * LDV + swc] = f2bf(pv[j].z);
      Vt[(4 * c4 + 3) * LDV + swc] = f2bf(pv[j].w);
    }
    __syncthreads();
    if (kt + 1 < N_KT) {
      const float4* kg = (const float4*)(k + hoff + (size_t)(kt + 1) * 64 * D_DIM);
      const float4* vg = (const float4*)(v + hoff + (size_t)(kt + 1) * 64 * D_DIM);
#pragma unroll
      for (int j = 0; j < 4; ++j) { pk[j] = kg[t + j * 256]; pv[j] = vg[t + j * 256]; }
    }
    int4 mq[2][4];
#pragma unroll
    for (int kb = 0; kb < 2; ++kb)
#pragma unroll
      for (int g = 0; g < 4; ++g)
        mq[kb][g] = *(const int4*)(mrow + kt * 64 + kb * 32 + g * 8 + hl * 4);
    f32x16 sT0 = zero16(), sT1 = zero16();
#pragma unroll
    for (int ks = 0; ks < 4; ++ks) {
      const bf16x8 aK0 = *(const bf16x8*)&Ks[col * LDK + ks * 16 + hl * 8];
      const bf16x8 aK1 = *(const bf16x8*)&Ks[(32 + col) * LDK + ks * 16 + hl * 8];
      sT0 = __builtin_amdgcn_mfma_f32_32x32x16_bf16(aK0, bQ[ks], sT0, 0, 0, 0);
      sT1 = __builtin_amdgcn_mfma_f32_32x32x16_bf16(aK1, bQ[ks], sT1, 0, 0, 0);
    }
    unsigned pw[2][8];
#pragma unroll
    for (int kb = 0; kb < 2; ++kb) {
      const f32x16 sT = kb ? sT1 : sT0;
      float e[16];
#pragma unroll
      for (int g = 0; g < 4; ++g) {
        const int4 mv = mq[kb][g];
        const int* mvp = &mv.x;
#pragma unroll
        for (int r3 = 0; r3 < 4; ++r3) {
          const int reg = g * 4 + r3;
          const float bias = mvp[r3] ? CM : 0.0f;
          const float ev = __builtin_amdgcn_exp2f(fmaf(sT[reg], C1, bias));
          e[reg] = ev;
          lacc += ev;
        }
        pw[kb][g * 2 + 0] = packbf(e[g * 4 + 0], e[g * 4 + 1]);
        pw[kb][g * 2 + 1] = packbf(e[g * 4 + 2], e[g * 4 + 3]);
      }
    }
#pragma unroll
    for (int ks = 0; ks < 4; ++ks) {
      const int kb = ks >> 1, h = ks & 1;
      const unsigned d0 = pw[kb][4 * h + 0], d1 = pw[kb][4 * h + 1];
      const unsigned d2 = pw[kb][4 * h + 2], d3 = pw[kb][4 * h + 3];
      const unsigned s0 = hl ? d0 : d2;
      const unsigned s1 = hl ? d1 : d3;
      const unsigned r0 = (unsigned)__shfl_xor((int)s0, 32);
      const unsigned r1 = (unsigned)__shfl_xor((int)s1, 32);
      union { bf16x8 v; unsigned d[4]; } pf;
      pf.d[0] = hl ? r0 : d0;
      pf.d[1] = hl ? r1 : d1;
      pf.d[2] = hl ? d2 : r0;
      pf.d[3] = hl ? d3 : r1;
      const int cpr = 8 * (((2 * ks + hl) + sw) & 7);
      const bf16x8 aV0 = *(const bf16x8*)&Vt[col * LDV + cpr];
      const bf16x8 aV1 = *(const bf16x8*)&Vt[(32 + col) * LDV + cpr];
      oT0 = __builtin_amdgcn_mfma_f32_32x32x16_bf16(aV0, pf.v, oT0, 0, 0, 0);
      oT1 = __builtin_amdgcn_mfma_f32_32x32x16_bf16(aV1, pf.v, oT1, 0, 0, 0);
    }
  }
  const float ltot = lacc + __shfl_xor(lacc, 32);
  const float inv = 1.0f / ltot;
  float* orow = out + hoff + (size_t)qg * D_DIM;
#pragma unroll
  for (int rg = 0; rg < 4; ++rg) {
    float4 w0, w1;
    w0.x = oT0[rg * 4 + 0] * inv; w0.y = oT0[rg * 4 + 1] * inv;
    w0.z = oT0[rg * 4 + 2] * inv; w0.w = oT0[rg * 4 + 3] * inv;
    w1.x = oT1[rg * 4 + 0] * inv; w1.y = oT1[rg * 4 + 1] * inv;
    w1.z = oT1[rg * 4 + 2] * inv; w1.w = oT1[rg * 4 + 3] * inv;
    *(float4*)(orow + 8 * rg + 4 * hl) = w0;
    *(float4*)(orow + 32 + 8 * rg + 4 * hl) = w1;
  }
}

extern "C" void kernel_launch(void* const* d_in, const int* in_sizes, int n_in,
                              void* d_out, int out_size, void* d_ws, size_t ws_size,
                              hipStream_t stream) {
  const float* q = (const float*)d_in[0];
  const float* k = (const float*)d_in[1];
  const float* v = (const float*)d_in[2];
  const int* mask = (const int*)d_in[3];
  float* out = (float*)d_out;

  const size_t mw_words = (size_t)S_LEN * 2 * N_KT * 16;  // u32 count (8 MB)
  const size_t need = mw_words * 4;

  if (ws_size >= need) {
    u32* mwp = (u32*)d_ws;
    prep_mask<<<dim3((S_LEN * 2 * N_KT * 4) / 256), dim3(256), 0, stream>>>(mask, mwp);
    attn_fwd<<<dim3(S_LEN / 64, NBH), dim3(256), 0, stream>>>(q, k, v, mwp, out);
  } else {
    attn_fwd_self<<<dim3(S_LEN / 128, NBH), dim3(256), 0, stream>>>(q, k, v, mask, out);
  }
}

// Round 15
// 167.104 us; speedup vs baseline: 1.2303x; 1.2303x over previous
//
#include <hip/hip_runtime.h>

// BaseAttention: B=2 H=16 S=2048 D=64, fp32 in/out.
// Round 19: 2 KV-tiles (128 keys) per barrier interval -- halve iterations.
//   r18 post-mortem: self-staging regressed (fp32 loads 2x bytes, scatter
//   conflicts, staging VALU between barriers); and the ~80-90us total-attn
//   residue SURVIVED prep_kv removal => fixed harness floor, attn_fwd is the
//   only lever. Five structures pin at 77us = 32 iters x ~5800cyc wall vs
//   ~750cyc dependent work: per-iteration fixed cost dominates and no counter
//   lever touched it. Untested axis: iteration count.
//   This round: r17's thrice-validated pipeline verbatim (frag image from
//   fused prep, counted entry vmcnt, exit lgkmcnt(0)+barrier with
//   [masks-asm, stage-dma16] cluster), scaled x2: 4 staging bufs (64KB, 2
//   blocks/CU -- r8 proved 8 waves/CU suffices), 16 iterations, per-iter
//   computes tile A then tile B. Steady entry vmcnt(8) (leaves the 8 stage
//   dmas of the newest exit group in flight; masks older => landed), iter15
//   vmcnt(0). Kept: XCD swizzle, ones-A MFMA l, setprio, kh-split waves,
//   Q pre-scaled 0.125*log2e, mask AND-words, pkrtz f16 P, LDS-alias epilogue.
//   Kill: attn >= 72us => iteration-count theory dead, structural floor.

#define S_LEN 2048
#define D_DIM 64
#define N_KT 32
#define NBH 32
#define TILE_SEGS 16
#define TILE_SHORTS 8192                 // 16 KB: [K frags 4096][V frags 4096]
#define SEG_U32 256                      // 1024 B per seg (64 lanes x 16 B)

typedef __attribute__((ext_vector_type(8))) short bf16x8;
typedef __attribute__((ext_vector_type(16))) float f32x16;
typedef __attribute__((ext_vector_type(2))) __fp16 fp16x2;
typedef unsigned int u32;

#define C1 0.180336880111121f    // 0.125 * log2(e)
#define CM (-14426.9504088896f)  // -10000 * log2(e)  (fallback kernel only)

static __device__ __forceinline__ unsigned short f2bf(float f) {
  union { float f; unsigned u; } x; x.f = f;
  return (unsigned short)((x.u + 0x8000u) >> 16);
}
static __device__ __forceinline__ unsigned packbf(float lo, float hi) {
  union { float f; unsigned u; } a, b; a.f = lo; b.f = hi;
  return ((a.u + 0x8000u) >> 16) | ((b.u + 0x8000u) & 0xffff0000u);
}
static __device__ __forceinline__ f32x16 zero16() {
  f32x16 z;
#pragma unroll
  for (int i = 0; i < 16; ++i) z[i] = 0.f;
  return z;
}
static __device__ __forceinline__ void dma16(const u32* g, u32* l) {
  __builtin_amdgcn_global_load_lds(
      (const __attribute__((address_space(1))) u32*)g,
      (__attribute__((address_space(3))) u32*)l, 16, 0, 0);
}
static __device__ __forceinline__ unsigned pkh(float lo, float hi) {
  union { fp16x2 h; unsigned u; } x;
  x.h = __builtin_amdgcn_cvt_pkrtz(lo, hi);
  return x.u;
}

// ---- fused pre-pass: blocks [0,1024): K,V frag image; [1024,3072): mask ----
// (r14-validated, unchanged)
__global__ __launch_bounds__(256) void prep_fused(
    const float* __restrict__ k, const float* __restrict__ v,
    const int* __restrict__ mask, unsigned short* __restrict__ kvws,
    u32* __restrict__ mw) {
  __shared__ unsigned short Kr[64 * 72];
  __shared__ unsigned short Vr[64 * 72];
  const int blk = blockIdx.x;
  const int t = threadIdx.x;
  if (blk < N_KT * NBH) {
    const int kt = blk & 31, bh = blk >> 5;
    const size_t goff = (size_t)bh * (S_LEN * D_DIM) + (size_t)kt * 64 * D_DIM;
    const float4* kg = (const float4*)(k + goff);
    const float4* vg = (const float4*)(v + goff);
#pragma unroll
    for (int j = 0; j < 4; ++j) {
      const int i = t + j * 256;
      const int row = i >> 4, c4 = i & 15;  // row = key, c4 = d-group
      const float4 x = kg[i];
      ushort4 w;
      w.x = f2bf(x.x); w.y = f2bf(x.y); w.z = f2bf(x.z); w.w = f2bf(x.w);
      *(ushort4*)&Kr[row * 72 + c4 * 4] = w;
      const float4 y = vg[i];
      const unsigned p01 = pkh(y.x, y.y), p23 = pkh(y.z, y.w);
      uint2 vv; vv.x = p01; vv.y = p23;
      *(uint2*)&Vr[row * 72 + c4 * 4] = vv;
    }
    __syncthreads();
    uint4* img = (uint4*)(kvws + (size_t)(bh * N_KT + kt) * TILE_SHORTS);
    for (int c = t; c < 512; c += 256) {
      const int col = c & 31, hlc = (c >> 5) & 1, ks = (c >> 6) & 3, khc = c >> 8;
      img[c] = *(const uint4*)&Kr[(khc * 32 + col) * 72 + ks * 16 + hlc * 8];
    }
    for (int c = t; c < 512; c += 256) {
      const int col = c & 31, b = (c >> 5) & 1, hlc = (c >> 6) & 1, kcHi = c >> 7;
      const int d = b * 32 + col, kk = (2 * kcHi + hlc) * 8;
      union { unsigned short s[8]; uint4 u; } o;
#pragma unroll
      for (int jj = 0; jj < 8; ++jj) o.s[jj] = Vr[(kk + jj) * 72 + d];
      img[512 + c] = o.u;
    }
  } else {
    const int gt = (blk - N_KT * NBH) * 256 + t;  // 524288 total
    const int q4 = gt & 3;
    const int kt = (gt >> 2) & 31;
    const int hl = (gt >> 7) & 1;
    const int row = gt >> 8;
    const int j0 = kt * 64 + 32 * (q4 >> 1) + 16 * (q4 & 1) + 4 * hl;
    const int* mr = mask + (size_t)row * S_LEN;
    const int4 a = *(const int4*)(mr + j0);
    const int4 b = *(const int4*)(mr + j0 + 8);
    uint4 w;
    w.x = (a.x == 0 ? 0x0000FFFFu : 0u) | (a.y == 0 ? 0xFFFF0000u : 0u);
    w.y = (a.z == 0 ? 0x0000FFFFu : 0u) | (a.w == 0 ? 0xFFFF0000u : 0u);
    w.z = (b.x == 0 ? 0x0000FFFFu : 0u) | (b.y == 0 ? 0xFFFF0000u : 0u);
    w.w = (b.z == 0 ? 0x0000FFFFu : 0u) | (b.w == 0 ? 0xFFFF0000u : 0u);
    *(uint4*)&mw[((size_t)(row * 2 + hl) * N_KT + kt) * 16 + q4 * 4] = w;
  }
}

// ---- main: 2 tiles per barrier interval, counted-vmcnt DMA pipeline ----
__global__ __launch_bounds__(256, 2) void attn_fwd(
    const float* __restrict__ q, const unsigned short* __restrict__ kvws,
    const u32* __restrict__ mw, float* __restrict__ out) {
  // XCD swizzle (r17-validated): XCD x hosts bh in [4x,4x+4) x all qt.
  const int lin = blockIdx.x + 32 * blockIdx.y;
  const int xcd = lin & 7;
  const int wk = lin >> 3;
  const int qt = wk & 31;
  const int bh = xcd * 4 + (wk >> 5);
  const size_t hoff = (size_t)bh * (S_LEN * D_DIM);

  __shared__ unsigned short sbuf[4][TILE_SHORTS];  // 4 x 16 KB = 64 KB

  const int t = threadIdx.x;
  const int wave = t >> 6;
  const int lane = t & 63;
  const int col = lane & 31;
  const int hl = lane >> 5;
  const int qh = wave >> 1;  // q half
  const int kh = wave & 1;   // key half of each tile
  const int qg = qt * 64 + qh * 32 + col;

  // Q^T B-fragments, PRE-SCALED by C1
  bf16x8 bQ[4];
  {
    const float* qrow = q + hoff + (size_t)qg * D_DIM;
#pragma unroll
    for (int ks = 0; ks < 4; ++ks) {
      const float4 x0 = *(const float4*)(qrow + ks * 16 + hl * 8);
      const float4 x1 = *(const float4*)(qrow + ks * 16 + hl * 8 + 4);
      union { bf16x8 v; unsigned d[4]; } u;
      u.d[0] = packbf(x0.x * C1, x0.y * C1);
      u.d[1] = packbf(x0.z * C1, x0.w * C1);
      u.d[2] = packbf(x1.x * C1, x1.y * C1);
      u.d[3] = packbf(x1.z * C1, x1.w * C1);
      bQ[ks] = u.v;
    }
  }

  // ones A-fragment (f16 1.0) for the l row-sum MFMA
  bf16x8 onesA;
  {
    union { bf16x8 v; unsigned d[4]; } u;
    u.d[0] = u.d[1] = u.d[2] = u.d[3] = 0x3C003C00u;
    onesA = u.v;
  }

  f32x16 oT0 = zero16(), oT1 = zero16(), oL = zero16();
  const uint4* mrow = (const uint4*)(mw + (size_t)(qg * 2 + hl) * N_KT * 16);
  const u32* img = (const u32*)(kvws + (size_t)bh * N_KT * TILE_SHORTS);
  const int seg0 = wave * 4;  // this wave's 4 segments of each 16-seg tile

  // one compute pass over one staged tile
  auto tile_body = [&](const unsigned short* base, const u32* mwv) {
    const unsigned short* Ksb = base;
    const unsigned short* Vtb = base + 4096;
    f32x16 sT = zero16();
    __builtin_amdgcn_s_setprio(1);
#pragma unroll
    for (int ks = 0; ks < 4; ++ks) {
      const bf16x8 aK =
          *(const bf16x8*)&Ksb[kh * 2048 + ks * 512 + hl * 256 + col * 8];
      sT = __builtin_amdgcn_mfma_f32_32x32x16_bf16(aK, bQ[ks], sT, 0, 0, 0);
    }
    __builtin_amdgcn_s_setprio(0);
    unsigned pw[8];
#pragma unroll
    for (int g2 = 0; g2 < 4; ++g2) {
      const float e0 = __builtin_amdgcn_exp2f(sT[g2 * 4 + 0]);
      const float e1 = __builtin_amdgcn_exp2f(sT[g2 * 4 + 1]);
      const float e2 = __builtin_amdgcn_exp2f(sT[g2 * 4 + 2]);
      const float e3 = __builtin_amdgcn_exp2f(sT[g2 * 4 + 3]);
      pw[g2 * 2 + 0] = pkh(e0, e1) & mwv[g2 * 2 + 0];
      pw[g2 * 2 + 1] = pkh(e2, e3) & mwv[g2 * 2 + 1];
    }
    __builtin_amdgcn_s_setprio(1);
#pragma unroll
    for (int ks2 = 0; ks2 < 2; ++ks2) {
      const unsigned d0 = pw[4 * ks2 + 0], d1 = pw[4 * ks2 + 1];
      const unsigned d2 = pw[4 * ks2 + 2], d3 = pw[4 * ks2 + 3];
      const unsigned s0 = hl ? d0 : d2;
      const unsigned s1 = hl ? d1 : d3;
      const unsigned r0 = (unsigned)__shfl_xor((int)s0, 32);
      const unsigned r1 = (unsigned)__shfl_xor((int)s1, 32);
      union { bf16x8 v; unsigned d[4]; } pf;
      pf.d[0] = hl ? r0 : d0;
      pf.d[1] = hl ? r1 : d1;
      pf.d[2] = hl ? d2 : r0;
      pf.d[3] = hl ? d3 : r1;
      const int kcHi = kh * 2 + ks2;
      const bf16x8 aV0 =
          *(const bf16x8*)&Vtb[kcHi * 1024 + hl * 512 + 0 * 256 + col * 8];
      const bf16x8 aV1 =
          *(const bf16x8*)&Vtb[kcHi * 1024 + hl * 512 + 1 * 256 + col * 8];
      oT0 = __builtin_amdgcn_mfma_f32_32x32x16_f16(aV0, pf.v, oT0, 0, 0, 0);
      oT1 = __builtin_amdgcn_mfma_f32_32x32x16_f16(aV1, pf.v, oT1, 0, 0, 0);
      oL = __builtin_amdgcn_mfma_f32_32x32x16_f16(onesA, pf.v, oL, 0, 0, 0);
    }
    __builtin_amdgcn_s_setprio(0);
  };

  uint4 mqA0, mqA1, mqB0, mqB1;
  // prologue (r17 shape, x2): masks(t0,t1) FIRST, then stage t0..t3.
  {
    const uint4* mpA = mrow + 0 * 4 + kh * 2;
    const uint4* mpB = mrow + 1 * 4 + kh * 2;
    asm volatile("global_load_dwordx4 %0, %4, off\n\t"
                 "global_load_dwordx4 %1, %5, off\n\t"
                 "global_load_dwordx4 %2, %6, off\n\t"
                 "global_load_dwordx4 %3, %7, off"
                 : "=&v"(mqA0), "=&v"(mqA1), "=&v"(mqB0), "=&v"(mqB1)
                 : "v"(mpA), "v"(mpA + 1), "v"(mpB), "v"(mpB + 1)
                 : "memory");
  }
#pragma unroll
  for (int tb = 0; tb < 4; ++tb)
#pragma unroll
    for (int s = 0; s < 4; ++s)
      dma16(img + (size_t)tb * (TILE_SEGS * SEG_U32) +
                (size_t)(seg0 + s) * SEG_U32 + lane * 4,
            (u32*)&sbuf[tb][0] + (seg0 + s) * SEG_U32);

  for (int it = 0; it < N_KT / 2; ++it) {
    const int pA = (it & 1) * 2;          // tile 2*it  lives in buf[(2it)%4]
    const int pB = pA + 1;                // tile 2*it+1
    // entry: tiles A,B + their masks landed; newest 8 stage dmas in flight
    if (it < N_KT / 2 - 1) {
      asm volatile("s_waitcnt vmcnt(8)" ::: "memory");
    } else {
      asm volatile("s_waitcnt vmcnt(0)" ::: "memory");
    }
    __builtin_amdgcn_s_barrier();
    __builtin_amdgcn_sched_barrier(0);

    const u32 mwvA[8] = {mqA0.x, mqA0.y, mqA0.z, mqA0.w,
                         mqA1.x, mqA1.y, mqA1.z, mqA1.w};
    const u32 mwvB[8] = {mqB0.x, mqB0.y, mqB0.z, mqB0.w,
                         mqB1.x, mqB1.y, mqB1.z, mqB1.w};

    tile_body(&sbuf[pA][0], mwvA);
    tile_body(&sbuf[pB][0], mwvB);

    // exit: reads of bufs A,B done -> re-stage them; masks FIRST (r17 shape)
    if (it < N_KT / 2 - 1) {
      asm volatile("s_waitcnt lgkmcnt(0)" ::: "memory");
      __builtin_amdgcn_s_barrier();
      __builtin_amdgcn_sched_barrier(0);
      {
        const int tA = 2 * it + 2, tB = 2 * it + 3;
        const uint4* mpA = mrow + tA * 4 + kh * 2;
        const uint4* mpB = mrow + tB * 4 + kh * 2;
        asm volatile("global_load_dwordx4 %0, %4, off\n\t"
                     "global_load_dwordx4 %1, %5, off\n\t"
                     "global_load_dwordx4 %2, %6, off\n\t"
                     "global_load_dwordx4 %3, %7, off"
                     : "=&v"(mqA0), "=&v"(mqA1), "=&v"(mqB0), "=&v"(mqB1)
                     : "v"(mpA), "v"(mpA + 1), "v"(mpB), "v"(mpB + 1)
                     : "memory");
      }
      if (it < N_KT / 2 - 2) {
        const int tA = 2 * it + 4, tB = 2 * it + 5;
        const u32* gA = img + (size_t)tA * (TILE_SEGS * SEG_U32);
        const u32* gB = img + (size_t)tB * (TILE_SEGS * SEG_U32);
#pragma unroll
        for (int s = 0; s < 4; ++s)
          dma16(gA + (size_t)(seg0 + s) * SEG_U32 + lane * 4,
                (u32*)&sbuf[pA][0] + (seg0 + s) * SEG_U32);
#pragma unroll
        for (int s = 0; s < 4; ++s)
          dma16(gB + (size_t)(seg0 + s) * SEG_U32 + lane * 4,
                (u32*)&sbuf[pB][0] + (seg0 + s) * SEG_U32);
      }
    }
  }

  // ---- cross-wave key-half reduction via LDS alias over sbuf ----
  __syncthreads();  // all tile reads done; sbuf free to alias
  {
    float* xb = (float*)&sbuf[0][0];                     // 17408 B
    float* lb = (float*)((char*)&sbuf[0][0] + 17408);    // 256 B
    float* xr = xb + (size_t)(qh * 32 + col) * 68;
    if (kh) {
#pragma unroll
      for (int rg = 0; rg < 4; ++rg) {
        float4 w0, w1;
        w0.x = oT0[rg * 4 + 0]; w0.y = oT0[rg * 4 + 1];
        w0.z = oT0[rg * 4 + 2]; w0.w = oT0[rg * 4 + 3];
        w1.x = oT1[rg * 4 + 0]; w1.y = oT1[rg * 4 + 1];
        w1.z = oT1[rg * 4 + 2]; w1.w = oT1[rg * 4 + 3];
        *(float4*)(xr + 8 * rg + 4 * hl) = w0;
        *(float4*)(xr + 32 + 8 * rg + 4 * hl) = w1;
      }
      if (!hl) lb[qh * 32 + col] = oL[0];  // every C row of ones*P^T = l(q=col)
    }
    __syncthreads();
    if (!kh) {
      const float inv = 1.0f / (oL[0] + lb[qh * 32 + col]);
      float* orow = out + hoff + (size_t)qg * D_DIM;
#pragma unroll
      for (int rg = 0; rg < 4; ++rg) {
        const float4 a0 = *(const float4*)(xr + 8 * rg + 4 * hl);
        const float4 a1 = *(const float4*)(xr + 32 + 8 * rg + 4 * hl);
        float4 w0, w1;
        w0.x = (oT0[rg * 4 + 0] + a0.x) * inv;
        w0.y = (oT0[rg * 4 + 1] + a0.y) * inv;
        w0.z = (oT0[rg * 4 + 2] + a0.z) * inv;
        w0.w = (oT0[rg * 4 + 3] + a0.w) * inv;
        w1.x = (oT1[rg * 4 + 0] + a1.x) * inv;
        w1.y = (oT1[rg * 4 + 1] + a1.y) * inv;
        w1.z = (oT1[rg * 4 + 2] + a1.z) * inv;
        w1.w = (oT1[rg * 4 + 3] + a1.w) * inv;
        *(float4*)(orow + 8 * rg + 4 * hl) = w0;
        *(float4*)(orow + 32 + 8 * rg + 4 * hl) = w1;
      }
    }
  }
}

// ---- fallback (round-4 kernel, self-staging) if ws is too small ----
#define LDK 72
#define LDV 72
__global__ __launch_bounds__(256, 2) void attn_fwd_self(
    const float* __restrict__ q, const float* __restrict__ k,
    const float* __restrict__ v, const int* __restrict__ mask,
    float* __restrict__ out) {
  const int qt = blockIdx.x;
  const int bh = blockIdx.y;
  const size_t hoff = (size_t)bh * (S_LEN * D_DIM);
  __shared__ unsigned short Ks[64 * LDK];
  __shared__ unsigned short Vt[64 * LDV];
  const int t = threadIdx.x;
  const int wave = t >> 6;
  const int lane = t & 63;
  const int col = lane & 31;
  const int hl = lane >> 5;
  const int sw = col >> 2;
  const int qg = qt * 128 + wave * 32 + col;
  bf16x8 bQ[4];
  {
    const float* qrow = q + hoff + (size_t)qg * D_DIM;
#pragma unroll
    for (int ks = 0; ks < 4; ++ks) {
      const float4 x0 = *(const float4*)(qrow + ks * 16 + hl * 8);
      const float4 x1 = *(const float4*)(qrow + ks * 16 + hl * 8 + 4);
      union { bf16x8 v; unsigned d[4]; } u;
      u.d[0] = packbf(x0.x, x0.y);
      u.d[1] = packbf(x0.z, x0.w);
      u.d[2] = packbf(x1.x, x1.y);
      u.d[3] = packbf(x1.z, x1.w);
      bQ[ks] = u.v;
    }
  }
  float4 pk[4], pv[4];
  {
    const float4* kg = (const float4*)(k + hoff);
    const float4* vg = (const float4*)(v + hoff);
#pragma unroll
    for (int j = 0; j < 4; ++j) { pk[j] = kg[t + j * 256]; pv[j] = vg[t + j * 256]; }
  }
  f32x16 oT0 = zero16(), oT1 = zero16();
  float lacc = 0.f;
  const int* mrow = mask + (size_t)qg * S_LEN;
  for (int kt = 0; kt < N_KT; ++kt) {
    __syncthreads();
#pragma unroll
    for (int j = 0; j < 4; ++j) {
      const int i = t + j * 256;
      const int row = i >> 4, c4 = i & 15;
      ushort4 w;
      w.x = f2bf(pk[j].x); w.y = f2bf(pk[j].y);
      w.z = f2bf(pk[j].z); w.w = f2bf(pk[j].w);
      *(ushort4*)&Ks[row * LDK + c4 * 4] = w;
      const int swc = 8 * (((row >> 3) + c4) & 7) + (row & 7);
      Vt[(4 * c4 + 0) * LDV + swc] = f2bf(pv[j].x);
      Vt[(4 * c4 + 1) * LDV + swc] = f2bf(pv[j].y);
      Vt[(4 * c4 + 2) * LDV + swc] = f2bf(pv[j].z);
      Vt[(4 * c4 + 3) * LDV + swc] = f2bf(pv[j].w);
    }
    __syncthreads();
    if (kt + 1 < N_KT) {
      const float4* kg = (const float4*)(k + hoff + (size_t)(kt + 1) * 64 * D_DIM);
      const float4* vg = (const float4*)(v + hoff + (size_t)(kt + 1) * 64 * D_DIM);
#pragma unroll
      for (int j = 0; j < 4; ++j) { pk[j] = kg[t + j * 256]; pv[j] = vg[t + j * 256]; }
    }
    int4 mq[2][4];
#pragma unroll
    for (int kb = 0; kb < 2; ++kb)
#pragma unroll
      for (int g = 0; g < 4; ++g)
        mq[kb][g] = *(const int4*)(mrow + kt * 64 + kb * 32 + g * 8 + hl * 4);
    f32x16 sT0 = zero16(), sT1 = zero16();
#pragma unroll
    for (int ks = 0; ks < 4; ++ks) {
      const bf16x8 aK0 = *(const bf16x8*)&Ks[col * LDK + ks * 16 + hl * 8];
      const bf16x8 aK1 = *(const bf16x8*)&Ks[(32 + col) * LDK + ks * 16 + hl * 8];
      sT0 = __builtin_amdgcn_mfma_f32_32x32x16_bf16(aK0, bQ[ks], sT0, 0, 0, 0);
      sT1 = __builtin_amdgcn_mfma_f32_32x32x16_bf16(aK1, bQ[ks], sT1, 0, 0, 0);
    }
    unsigned pw[2][8];
#pragma unroll
    for (int kb = 0; kb < 2; ++kb) {
      const f32x16 sT = kb ? sT1 : sT0;
      float e[16];
#pragma unroll
      for (int g = 0; g < 4; ++g) {
        const int4 mv = mq[kb][g];
        const int* mvp = &mv.x;
#pragma unroll
        for (int r3 = 0; r3 < 4; ++r3) {
          const int reg = g * 4 + r3;
          const float bias = mvp[r3] ? CM : 0.0f;
          const float ev = __builtin_amdgcn_exp2f(fmaf(sT[reg], C1, bias));
          e[reg] = ev;
          lacc += ev;
        }
        pw[kb][g * 2 + 0] = packbf(e[g * 4 + 0], e[g * 4 + 1]);
        pw[kb][g * 2 + 1] = packbf(e[g * 4 + 2], e[g * 4 + 3]);
      }
    }
#pragma unroll
    for (int ks = 0; ks < 4; ++ks) {
      const int kb = ks >> 1, h = ks & 1;
      const unsigned d0 = pw[kb][4 * h + 0], d1 = pw[kb][4 * h + 1];
      const unsigned d2 = pw[kb][4 * h + 2], d3 = pw[kb][4 * h + 3];
      const unsigned s0 = hl ? d0 : d2;
      const unsigned s1 = hl ? d1 : d3;
      const unsigned r0 = (unsigned)__shfl_xor((int)s0, 32);
      const unsigned r1 = (unsigned)__shfl_xor((int)s1, 32);
      union { bf16x8 v; unsigned d[4]; } pf;
      pf.d[0] = hl ? r0 : d0;
      pf.d[1] = hl ? r1 : d1;
      pf.d[2] = hl ? d2 : r0;
      pf.d[3] = hl ? d3 : r1;
      const int cpr = 8 * (((2 * ks + hl) + sw) & 7);
      const bf16x8 aV0 = *(const bf16x8*)&Vt[col * LDV + cpr];
      const bf16x8 aV1 = *(const bf16x8*)&Vt[(32 + col) * LDV + cpr];
      oT0 = __builtin_amdgcn_mfma_f32_32x32x16_bf16(aV0, pf.v, oT0, 0, 0, 0);
      oT1 = __builtin_amdgcn_mfma_f32_32x32x16_bf16(aV1, pf.v, oT1, 0, 0, 0);
    }
  }
  const float ltot = lacc + __shfl_xor(lacc, 32);
  const float inv = 1.0f / ltot;
  float* orow = out + hoff + (size_t)qg * D_DIM;
#pragma unroll
  for (int rg = 0; rg < 4; ++rg) {
    float4 w0, w1;
    w0.x = oT0[rg * 4 + 0] * inv; w0.y = oT0[rg * 4 + 1] * inv;
    w0.z = oT0[rg * 4 + 2] * inv; w0.w = oT0[rg * 4 + 3] * inv;
    w1.x = oT1[rg * 4 + 0] * inv; w1.y = oT1[rg * 4 + 1] * inv;
    w1.z = oT1[rg * 4 + 2] * inv; w1.w = oT1[rg * 4 + 3] * inv;
    *(float4*)(orow + 8 * rg + 4 * hl) = w0;
    *(float4*)(orow + 32 + 8 * rg + 4 * hl) = w1;
  }
}

extern "C" void kernel_launch(void* const* d_in, const int* in_sizes, int n_in,
                              void* d_out, int out_size, void* d_ws, size_t ws_size,
                              hipStream_t stream) {
  const float* q = (const float*)d_in[0];
  const float* k = (const float*)d_in[1];
  const float* v = (const float*)d_in[2];
  const int* mask = (const int*)d_in[3];
  float* out = (float*)d_out;

  const size_t kv_shorts = (size_t)NBH * N_KT * TILE_SHORTS;
  const size_t mw_words = (size_t)S_LEN * 2 * N_KT * 16;  // u32 count
  const size_t need = kv_shorts * sizeof(unsigned short) + mw_words * 4;

  if (ws_size >= need) {
    unsigned short* kvws = (unsigned short*)d_ws;
    u32* mwp = (u32*)(kvws + kv_shorts);
    prep_fused<<<dim3(N_KT * NBH + (S_LEN * 2 * N_KT * 4) / 256), dim3(256), 0,
                 stream>>>(k, v, mask, kvws, mwp);
    attn_fwd<<<dim3(S_LEN / 64, NBH), dim3(256), 0, stream>>>(q, kvws, mwp, out);
  } else {
    attn_fwd_self<<<dim3(S_LEN / 128, NBH), dim3(256), 0, stream>>>(q, k, v, mask, out);
  }
}

// Round 16
// 156.430 us; speedup vs baseline: 1.3143x; 1.0682x over previous
//
#include <hip/hip_runtime.h>

// BaseAttention: B=2 H=16 S=2048 D=64, fp32 in/out.
// Round 20: wave-contiguous mask layout on the r17 pipeline.
//   r19 kill: 2 tiles/interval = 81.5us (occupancy offset) -- iteration-count
//   theory dead. Six structures pin 76-82us with every counter lever spent.
//   Invariant across ALL rounds: mask loads are uncoalesced -- adjacent lanes
//   4KB apart => 64 lines per dwordx4 (16B used / 64B line), ~2048 lines per
//   CU-iteration (~35% of TA/L2 request budget) + 512MB effective L2 line
//   traffic -- invisible in FETCH_SIZE (L3-resident slab).
//   Fix: mask words stored per (qt,qh,kt,kh) wave-block, lane-contiguous:
//   uint4 o = (qt*2+qh)*8192 + kt*256 + kh*128 + hl*64 + col*2 + i4.
//   A wave's 2 loads/iter are adjacent, lane stride 32B => 32 hot lines.
//   Word content identical to r12-validated semantics: word p=kh*8+i4*4+j
//   masks keys base+{0,1},{2,3},{8,9},{10,11}, base=kt*64+32kh+16i4+4hl
//   (verified against consumer needs: keys 32kh+8g2+4hl+2parity+{0,1}).
//   Everything else = r17 verbatim (passed 77us): frag image, fused prep,
//   counted entry vmcnt(4), exit lgkmcnt(0)+barrier+[masks,stages], XCD
//   swizzle, ones-A MFMA l, setprio, kh-split 4-wave blocks, Q pre-scaled,
//   pkrtz f16 P, LDS-alias epilogue.
//   Kill: attn >= 74us => mask theory dead, architecture at structural floor.

#define S_LEN 2048
#define D_DIM 64
#define N_KT 32
#define NBH 32
#define TILE_SEGS 16
#define TILE_SHORTS 8192                 // 16 KB: [K frags 4096][V frags 4096]
#define SEG_U32 256                      // 1024 B per seg (64 lanes x 16 B)

typedef __attribute__((ext_vector_type(8))) short bf16x8;
typedef __attribute__((ext_vector_type(16))) float f32x16;
typedef __attribute__((ext_vector_type(2))) __fp16 fp16x2;
typedef unsigned int u32;

#define C1 0.180336880111121f    // 0.125 * log2(e)
#define CM (-14426.9504088896f)  // -10000 * log2(e)  (fallback kernel only)

static __device__ __forceinline__ unsigned short f2bf(float f) {
  union { float f; unsigned u; } x; x.f = f;
  return (unsigned short)((x.u + 0x8000u) >> 16);
}
static __device__ __forceinline__ unsigned packbf(float lo, float hi) {
  union { float f; unsigned u; } a, b; a.f = lo; b.f = hi;
  return ((a.u + 0x8000u) >> 16) | ((b.u + 0x8000u) & 0xffff0000u);
}
static __device__ __forceinline__ f32x16 zero16() {
  f32x16 z;
#pragma unroll
  for (int i = 0; i < 16; ++i) z[i] = 0.f;
  return z;
}
static __device__ __forceinline__ void dma16(const u32* g, u32* l) {
  __builtin_amdgcn_global_load_lds(
      (const __attribute__((address_space(1))) u32*)g,
      (__attribute__((address_space(3))) u32*)l, 16, 0, 0);
}
static __device__ __forceinline__ unsigned pkh(float lo, float hi) {
  union { fp16x2 h; unsigned u; } x;
  x.h = __builtin_amdgcn_cvt_pkrtz(lo, hi);
  return x.u;
}

// ---- fused pre-pass: blocks [0,1024): K,V frag image; [1024,3072): mask ----
// KV part r14-validated, unchanged. Mask part: NEW wave-contiguous layout.
__global__ __launch_bounds__(256) void prep_fused(
    const float* __restrict__ k, const float* __restrict__ v,
    const int* __restrict__ mask, unsigned short* __restrict__ kvws,
    u32* __restrict__ mw) {
  __shared__ unsigned short Kr[64 * 72];
  __shared__ unsigned short Vr[64 * 72];
  const int blk = blockIdx.x;
  const int t = threadIdx.x;
  if (blk < N_KT * NBH) {
    const int kt = blk & 31, bh = blk >> 5;
    const size_t goff = (size_t)bh * (S_LEN * D_DIM) + (size_t)kt * 64 * D_DIM;
    const float4* kg = (const float4*)(k + goff);
    const float4* vg = (const float4*)(v + goff);
#pragma unroll
    for (int j = 0; j < 4; ++j) {
      const int i = t + j * 256;
      const int row = i >> 4, c4 = i & 15;  // row = key, c4 = d-group
      const float4 x = kg[i];
      ushort4 w;
      w.x = f2bf(x.x); w.y = f2bf(x.y); w.z = f2bf(x.z); w.w = f2bf(x.w);
      *(ushort4*)&Kr[row * 72 + c4 * 4] = w;
      const float4 y = vg[i];
      const unsigned p01 = pkh(y.x, y.y), p23 = pkh(y.z, y.w);
      uint2 vv; vv.x = p01; vv.y = p23;
      *(uint2*)&Vr[row * 72 + c4 * 4] = vv;
    }
    __syncthreads();
    uint4* img = (uint4*)(kvws + (size_t)(bh * N_KT + kt) * TILE_SHORTS);
    for (int c = t; c < 512; c += 256) {
      const int col = c & 31, hlc = (c >> 5) & 1, ks = (c >> 6) & 3, khc = c >> 8;
      img[c] = *(const uint4*)&Kr[(khc * 32 + col) * 72 + ks * 16 + hlc * 8];
    }
    for (int c = t; c < 512; c += 256) {
      const int col = c & 31, b = (c >> 5) & 1, hlc = (c >> 6) & 1, kcHi = c >> 7;
      const int d = b * 32 + col, kk = (2 * kcHi + hlc) * 8;
      union { unsigned short s[8]; uint4 u; } o;
#pragma unroll
      for (int jj = 0; jj < 8; ++jj) o.s[jj] = Vr[(kk + jj) * 72 + d];
      img[512 + c] = o.u;
    }
  } else {
    // NEW mask layout: uint4 index o packs (qt,qh,kt,kh,hl,col,i4):
    //   o = (qt*2+qh)*8192 + kt*256 + kh*128 + hl*64 + col*2 + i4
    // uint4 o holds words p = kh*8 + i4*4 + {0..3} for row=qt*64+qh*32+col,
    // hl; word j masks keys base + {0,1},{2,3},{8,9},{10,11} with
    // base = kt*64 + 32*kh + 16*i4 + 4*hl  (r12-validated content).
    const int o = (blk - N_KT * NBH) * 256 + t;  // 524288 total
    const int i4 = o & 1;
    const int col = (o >> 1) & 31;
    const int hl = (o >> 6) & 1;
    const int kh = (o >> 7) & 1;
    const int kt = (o >> 8) & 31;
    const int qh = (o >> 13) & 1;
    const int qt = o >> 14;
    const int row = qt * 64 + qh * 32 + col;
    const int base_key = kt * 64 + 32 * kh + 16 * i4 + 4 * hl;
    const int* mr = mask + (size_t)row * S_LEN;
    const int4 a = *(const int4*)(mr + base_key);
    const int4 b = *(const int4*)(mr + base_key + 8);
    uint4 w;
    w.x = (a.x == 0 ? 0x0000FFFFu : 0u) | (a.y == 0 ? 0xFFFF0000u : 0u);
    w.y = (a.z == 0 ? 0x0000FFFFu : 0u) | (a.w == 0 ? 0xFFFF0000u : 0u);
    w.z = (b.x == 0 ? 0x0000FFFFu : 0u) | (b.y == 0 ? 0xFFFF0000u : 0u);
    w.w = (b.z == 0 ? 0x0000FFFFu : 0u) | (b.w == 0 ? 0xFFFF0000u : 0u);
    ((uint4*)mw)[o] = w;
  }
}

// ---- main: r17 pipeline, wave-contiguous mask addressing ----
__global__ __launch_bounds__(256, 4) void attn_fwd(
    const float* __restrict__ q, const unsigned short* __restrict__ kvws,
    const u32* __restrict__ mw, float* __restrict__ out) {
  // XCD swizzle (r17-validated): XCD x hosts bh in [4x,4x+4) x all qt.
  const int lin = blockIdx.x + 32 * blockIdx.y;
  const int xcd = lin & 7;
  const int wk = lin >> 3;
  const int qt = wk & 31;
  const int bh = xcd * 4 + (wk >> 5);
  const size_t hoff = (size_t)bh * (S_LEN * D_DIM);

  __shared__ unsigned short sbuf[2][TILE_SHORTS];  // 2 x 16 KB

  const int t = threadIdx.x;
  const int wave = t >> 6;
  const int lane = t & 63;
  const int col = lane & 31;
  const int hl = lane >> 5;
  const int qh = wave >> 1;  // q half
  const int kh = wave & 1;   // key half of each tile
  const int qg = qt * 64 + qh * 32 + col;

  // Q^T B-fragments, PRE-SCALED by C1
  bf16x8 bQ[4];
  {
    const float* qrow = q + hoff + (size_t)qg * D_DIM;
#pragma unroll
    for (int ks = 0; ks < 4; ++ks) {
      const float4 x0 = *(const float4*)(qrow + ks * 16 + hl * 8);
      const float4 x1 = *(const float4*)(qrow + ks * 16 + hl * 8 + 4);
      union { bf16x8 v; unsigned d[4]; } u;
      u.d[0] = packbf(x0.x * C1, x0.y * C1);
      u.d[1] = packbf(x0.z * C1, x0.w * C1);
      u.d[2] = packbf(x1.x * C1, x1.y * C1);
      u.d[3] = packbf(x1.z * C1, x1.w * C1);
      bQ[ks] = u.v;
    }
  }

  // ones A-fragment (f16 1.0) for the l row-sum MFMA (r8/r17-validated)
  bf16x8 onesA;
  {
    union { bf16x8 v; unsigned d[4]; } u;
    u.d[0] = u.d[1] = u.d[2] = u.d[3] = 0x3C003C00u;
    onesA = u.v;
  }

  f32x16 oT0 = zero16(), oT1 = zero16(), oL = zero16();
  // wave-contiguous mask base: lane's uint4 pair for tile kt is at
  // mbase + kt*256 (+0, +1) -- lane stride 2 uint4 = 32 B, fully dense.
  const uint4* mbase = (const uint4*)mw + (size_t)(qt * 2 + qh) * 8192 +
                       kh * 128 + hl * 64 + col * 2;
  const u32* img = (const u32*)(kvws + (size_t)bh * N_KT * TILE_SHORTS);
  const int seg0 = wave * 4;  // this wave's 4 segments of each 16-seg tile

  uint4 mq0, mq1;
  // prologue vmem order (per wave): ml(0) x2, stage(0) x4, stage(1) x4.
  {
    const uint4* mp = mbase;  // kt = 0
    asm volatile("global_load_dwordx4 %0, %2, off\n\t"
                 "global_load_dwordx4 %1, %3, off"
                 : "=&v"(mq0), "=&v"(mq1)
                 : "v"(mp), "v"(mp + 1)
                 : "memory");
  }
#pragma unroll
  for (int s = 0; s < 4; ++s)
    dma16(img + (size_t)(seg0 + s) * SEG_U32 + lane * 4,
          (u32*)&sbuf[0][0] + (seg0 + s) * SEG_U32);
#pragma unroll
  for (int s = 0; s < 4; ++s)
    dma16(img + (size_t)(TILE_SEGS + seg0 + s) * SEG_U32 + lane * 4,
          (u32*)&sbuf[1][0] + (seg0 + s) * SEG_U32);

  for (int kt = 0; kt < N_KT; ++kt) {
    const int p = kt & 1;
    // entry: own stage(kt)+ml(kt) complete; stage(kt+1) stays in flight
    if (kt < N_KT - 1) {
      asm volatile("s_waitcnt vmcnt(4)" ::: "memory");
    } else {
      asm volatile("s_waitcnt vmcnt(0)" ::: "memory");
    }
    __builtin_amdgcn_s_barrier();
    __builtin_amdgcn_sched_barrier(0);

    const unsigned short* Ksb = &sbuf[p][0];
    const unsigned short* Vtb = &sbuf[p][4096];
    const u32 mwv[8] = {mq0.x, mq0.y, mq0.z, mq0.w,
                        mq1.x, mq1.y, mq1.z, mq1.w};

    // S^T = K Q^T : this wave's 32-key half x K=64 (pre-scaled via Q)
    f32x16 sT = zero16();
    __builtin_amdgcn_s_setprio(1);
#pragma unroll
    for (int ks = 0; ks < 4; ++ks) {
      const bf16x8 aK =
          *(const bf16x8*)&Ksb[kh * 2048 + ks * 512 + hl * 256 + col * 8];
      sT = __builtin_amdgcn_mfma_f32_32x32x16_bf16(aK, bQ[ks], sT, 0, 0, 0);
    }
    __builtin_amdgcn_s_setprio(0);

    // p = exp2(s), pack f16 (pkrtz), mask with AND-words
    unsigned pw[8];
#pragma unroll
    for (int g2 = 0; g2 < 4; ++g2) {
      const float e0 = __builtin_amdgcn_exp2f(sT[g2 * 4 + 0]);
      const float e1 = __builtin_amdgcn_exp2f(sT[g2 * 4 + 1]);
      const float e2 = __builtin_amdgcn_exp2f(sT[g2 * 4 + 2]);
      const float e3 = __builtin_amdgcn_exp2f(sT[g2 * 4 + 3]);
      pw[g2 * 2 + 0] = pkh(e0, e1) & mwv[g2 * 2 + 0];
      pw[g2 * 2 + 1] = pkh(e2, e3) & mwv[g2 * 2 + 1];
    }

    // O^T += Vt * P^T ; l += ones * P^T (exact row-sum of masked P)
    __builtin_amdgcn_s_setprio(1);
#pragma unroll
    for (int ks2 = 0; ks2 < 2; ++ks2) {
      const unsigned d0 = pw[4 * ks2 + 0], d1 = pw[4 * ks2 + 1];
      const unsigned d2 = pw[4 * ks2 + 2], d3 = pw[4 * ks2 + 3];
      const unsigned s0 = hl ? d0 : d2;
      const unsigned s1 = hl ? d1 : d3;
      const unsigned r0 = (unsigned)__shfl_xor((int)s0, 32);
      const unsigned r1 = (unsigned)__shfl_xor((int)s1, 32);
      union { bf16x8 v; unsigned d[4]; } pf;
      pf.d[0] = hl ? r0 : d0;
      pf.d[1] = hl ? r1 : d1;
      pf.d[2] = hl ? d2 : r0;
      pf.d[3] = hl ? d3 : r1;
      const int kcHi = kh * 2 + ks2;
      const bf16x8 aV0 =
          *(const bf16x8*)&Vtb[kcHi * 1024 + hl * 512 + 0 * 256 + col * 8];
      const bf16x8 aV1 =
          *(const bf16x8*)&Vtb[kcHi * 1024 + hl * 512 + 1 * 256 + col * 8];
      oT0 = __builtin_amdgcn_mfma_f32_32x32x16_f16(aV0, pf.v, oT0, 0, 0, 0);
      oT1 = __builtin_amdgcn_mfma_f32_32x32x16_f16(aV1, pf.v, oT1, 0, 0, 0);
      oL = __builtin_amdgcn_mfma_f32_32x32x16_f16(onesA, pf.v, oL, 0, 0, 0);
    }
    __builtin_amdgcn_s_setprio(0);

    // exit: reads of buf[p] done -> allow re-staging it; masks BEFORE dmas
    if (kt < N_KT - 1) {
      asm volatile("s_waitcnt lgkmcnt(0)" ::: "memory");
      __builtin_amdgcn_s_barrier();
      __builtin_amdgcn_sched_barrier(0);
      {
        const uint4* mp = mbase + (size_t)(kt + 1) * 256;
        asm volatile("global_load_dwordx4 %0, %2, off\n\t"
                     "global_load_dwordx4 %1, %3, off"
                     : "=&v"(mq0), "=&v"(mq1)
                     : "v"(mp), "v"(mp + 1)
                     : "memory");
      }
      if (kt < N_KT - 2) {
        const u32* g = img + (size_t)(kt + 2) * (TILE_SEGS * SEG_U32);
#pragma unroll
        for (int s = 0; s < 4; ++s)
          dma16(g + (size_t)(seg0 + s) * SEG_U32 + lane * 4,
                (u32*)&sbuf[p][0] + (seg0 + s) * SEG_U32);
      }
    }
  }

  // ---- cross-wave key-half reduction via LDS alias over sbuf ----
  __syncthreads();  // all tile reads done; sbuf free to alias
  {
    float* xb = (float*)&sbuf[0][0];                     // 17408 B
    float* lb = (float*)((char*)&sbuf[0][0] + 17408);    // 256 B
    float* xr = xb + (size_t)(qh * 32 + col) * 68;
    if (kh) {
#pragma unroll
      for (int rg = 0; rg < 4; ++rg) {
        float4 w0, w1;
        w0.x = oT0[rg * 4 + 0]; w0.y = oT0[rg * 4 + 1];
        w0.z = oT0[rg * 4 + 2]; w0.w = oT0[rg * 4 + 3];
        w1.x = oT1[rg * 4 + 0]; w1.y = oT1[rg * 4 + 1];
        w1.z = oT1[rg * 4 + 2]; w1.w = oT1[rg * 4 + 3];
        *(float4*)(xr + 8 * rg + 4 * hl) = w0;
        *(float4*)(xr + 32 + 8 * rg + 4 * hl) = w1;
      }
      if (!hl) lb[qh * 32 + col] = oL[0];  // every C row of ones*P^T = l(q=col)
    }
    __syncthreads();
    if (!kh) {
      const float inv = 1.0f / (oL[0] + lb[qh * 32 + col]);
      float* orow = out + hoff + (size_t)qg * D_DIM;
#pragma unroll
      for (int rg = 0; rg < 4; ++rg) {
        const float4 a0 = *(const float4*)(xr + 8 * rg + 4 * hl);
        const float4 a1 = *(const float4*)(xr + 32 + 8 * rg + 4 * hl);
        float4 w0, w1;
        w0.x = (oT0[rg * 4 + 0] + a0.x) * inv;
        w0.y = (oT0[rg * 4 + 1] + a0.y) * inv;
        w0.z = (oT0[rg * 4 + 2] + a0.z) * inv;
        w0.w = (oT0[rg * 4 + 3] + a0.w) * inv;
        w1.x = (oT1[rg * 4 + 0] + a1.x) * inv;
        w1.y = (oT1[rg * 4 + 1] + a1.y) * inv;
        w1.z = (oT1[rg * 4 + 2] + a1.z) * inv;
        w1.w = (oT1[rg * 4 + 3] + a1.w) * inv;
        *(float4*)(orow + 8 * rg + 4 * hl) = w0;
        *(float4*)(orow + 32 + 8 * rg + 4 * hl) = w1;
      }
    }
  }
}

// ---- fallback (round-4 kernel, self-staging) if ws is too small ----
#define LDK 72
#define LDV 72
__global__ __launch_bounds__(256, 2) void attn_fwd_self(
    const float* __restrict__ q, const float* __restrict__ k,
    const float* __restrict__ v, const int* __restrict__ mask,
    float* __restrict__ out) {
  const int qt = blockIdx.x;
  const int bh = blockIdx.y;
  const size_t hoff = (size_t)bh * (S_LEN * D_DIM);
  __shared__ unsigned short Ks[64 * LDK];
  __shared__ unsigned short Vt[64 * LDV];
  const int t = threadIdx.x;
  const int wave = t >> 6;
  const int lane = t & 63;
  const int col = lane & 31;
  const int hl = lane >> 5;
  const int sw = col >> 2;
  const int qg = qt * 128 + wave * 32 + col;
  bf16x8 bQ[4];
  {
    const float* qrow = q + hoff + (size_t)qg * D_DIM;
#pragma unroll
    for (int ks = 0; ks < 4; ++ks) {
      const float4 x0 = *(const float4*)(qrow + ks * 16 + hl * 8);
      const float4 x1 = *(const float4*)(qrow + ks * 16 + hl * 8 + 4);
      union { bf16x8 v; unsigned d[4]; } u;
      u.d[0] = packbf(x0.x, x0.y);
      u.d[1] = packbf(x0.z, x0.w);
      u.d[2] = packbf(x1.x, x1.y);
      u.d[3] = packbf(x1.z, x1.w);
      bQ[ks] = u.v;
    }
  }
  float4 pk[4], pv[4];
  {
    const float4* kg = (const float4*)(k + hoff);
    const float4* vg = (const float4*)(v + hoff);
#pragma unroll
    for (int j = 0; j < 4; ++j) { pk[j] = kg[t + j * 256]; pv[j] = vg[t + j * 256]; }
  }
  f32x16 oT0 = zero16(), oT1 = zero16();
  float lacc = 0.f;
  const int* mrow = mask + (size_t)qg * S_LEN;
  for (int kt = 0; kt < N_KT; ++kt) {
    __syncthreads();
#pragma unroll
    for (int j = 0; j < 4; ++j) {
      const int i = t + j * 256;
      const int row = i >> 4, c4 = i & 15;
      ushort4 w;
      w.x = f2bf(pk[j].x); w.y = f2bf(pk[j].y);
      w.z = f2bf(pk[j].z); w.w = f2bf(pk[j].w);
      *(ushort4*)&Ks[row * LDK + c4 * 4] = w;
      const int swc = 8 * (((row >> 3) + c4) & 7) + (row & 7);
      Vt[(4 * c4 + 0) * LDV + swc] = f2bf(pv[j].x);
      Vt[(4 * c4 + 1) * LDV + swc] = f2bf(pv[j].y);
      Vt[(4 * c4 + 2) * LDV + swc] = f2bf(pv[j].z);
      Vt[(4 * c4 + 3) * LDV + swc] = f2bf(pv[j].w);
    }
    __syncthreads();
    if (kt + 1 < N_KT) {
      const float4* kg = (const float4*)(k + hoff + (size_t)(kt + 1) * 64 * D_DIM);
      const float4* vg = (const float4*)(v + hoff + (size_t)(kt + 1) * 64 * D_DIM);
#pragma unroll
      for (int j = 0; j < 4; ++j) { pk[j] = kg[t + j * 256]; pv[j] = vg[t + j * 256]; }
    }
    int4 mq[2][4];
#pragma unroll
    for (int kb = 0; kb < 2; ++kb)
#pragma unroll
      for (int g = 0; g < 4; ++g)
        mq[kb][g] = *(const int4*)(mrow + kt * 64 + kb * 32 + g * 8 + hl * 4);
    f32x16 sT0 = zero16(), sT1 = zero16();
#pragma unroll
    for (int ks = 0; ks < 4; ++ks) {
      const bf16x8 aK0 = *(const bf16x8*)&Ks[col * LDK + ks * 16 + hl * 8];
      const bf16x8 aK1 = *(const bf16x8*)&Ks[(32 + col) * LDK + ks * 16 + hl * 8];
      sT0 = __builtin_amdgcn_mfma_f32_32x32x16_bf16(aK0, bQ[ks], sT0, 0, 0, 0);
      sT1 = __builtin_amdgcn_mfma_f32_32x32x16_bf16(aK1, bQ[ks], sT1, 0, 0, 0);
    }
    unsigned pw[2][8];
#pragma unroll
    for (int kb = 0; kb < 2; ++kb) {
      const f32x16 sT = kb ? sT1 : sT0;
      float e[16];
#pragma unroll
      for (int g = 0; g < 4; ++g) {
        const int4 mv = mq[kb][g];
        const int* mvp = &mv.x;
#pragma unroll
        for (int r3 = 0; r3 < 4; ++r3) {
          const int reg = g * 4 + r3;
          const float bias = mvp[r3] ? CM : 0.0f;
          const float ev = __builtin_amdgcn_exp2f(fmaf(sT[reg], C1, bias));
          e[reg] = ev;
          lacc += ev;
        }
        pw[kb][g * 2 + 0] = packbf(e[g * 4 + 0], e[g * 4 + 1]);
        pw[kb][g * 2 + 1] = packbf(e[g * 4 + 2], e[g * 4 + 3]);
      }
    }
#pragma unroll
    for (int ks = 0; ks < 4; ++ks) {
      const int kb = ks >> 1, h = ks & 1;
      const unsigned d0 = pw[kb][4 * h + 0], d1 = pw[kb][4 * h + 1];
      const unsigned d2 = pw[kb][4 * h + 2], d3 = pw[kb][4 * h + 3];
      const unsigned s0 = hl ? d0 : d2;
      const unsigned s1 = hl ? d1 : d3;
      const unsigned r0 = (unsigned)__shfl_xor((int)s0, 32);
      const unsigned r1 = (unsigned)__shfl_xor((int)s1, 32);
      union { bf16x8 v; unsigned d[4]; } pf;
      pf.d[0] = hl ? r0 : d0;
      pf.d[1] = hl ? r1 : d1;
      pf.d[2] = hl ? d2 : r0;
      pf.d[3] = hl ? d3 : r1;
      const int cpr = 8 * (((2 * ks + hl) + sw) & 7);
      const bf16x8 aV0 = *(const bf16x8*)&Vt[col * LDV + cpr];
      const bf16x8 aV1 = *(const bf16x8*)&Vt[(32 + col) * LDV + cpr];
      oT0 = __builtin_amdgcn_mfma_f32_32x32x16_bf16(aV0, pf.v, oT0, 0, 0, 0);
      oT1 = __builtin_amdgcn_mfma_f32_32x32x16_bf16(aV1, pf.v, oT1, 0, 0, 0);
    }
  }
  const float ltot = lacc + __shfl_xor(lacc, 32);
  const float inv = 1.0f / ltot;
  float* orow = out + hoff + (size_t)qg * D_DIM;
#pragma unroll
  for (int rg = 0; rg < 4; ++rg) {
    float4 w0, w1;
    w0.x = oT0[rg * 4 + 0] * inv; w0.y = oT0[rg * 4 + 1] * inv;
    w0.z = oT0[rg * 4 + 2] * inv; w0.w = oT0[rg * 4 + 3] * inv;
    w1.x = oT1[rg * 4 + 0] * inv; w1.y = oT1[rg * 4 + 1] * inv;
    w1.z = oT1[rg * 4 + 2] * inv; w1.w = oT1[rg * 4 + 3] * inv;
    *(float4*)(orow + 8 * rg + 4 * hl) = w0;
    *(float4*)(orow + 32 + 8 * rg + 4 * hl) = w1;
  }
}

extern "C" void kernel_launch(void* const* d_in, const int* in_sizes, int n_in,
                              void* d_out, int out_size, void* d_ws, size_t ws_size,
                              hipStream_t stream) {
  const float* q = (const float*)d_in[0];
  const float* k = (const float*)d_in[1];
  const float* v = (const float*)d_in[2];
  const int* mask = (const int*)d_in[3];
  float* out = (float*)d_out;

  const size_t kv_shorts = (size_t)NBH * N_KT * TILE_SHORTS;
  const size_t mw_words = (size_t)S_LEN * 2 * N_KT * 16;  // u32 count (8 MB)
  const size_t need = kv_shorts * sizeof(unsigned short) + mw_words * 4;

  if (ws_size >= need) {
    unsigned short* kvws = (unsigned short*)d_ws;
    u32* mwp = (u32*)(kvws + kv_shorts);
    prep_fused<<<dim3(N_KT * NBH + (S_LEN * 2 * N_KT * 4) / 256), dim3(256), 0,
                 stream>>>(k, v, mask, kvws, mwp);
    attn_fwd<<<dim3(S_LEN / 64, NBH), dim3(256), 0, stream>>>(q, kvws, mwp, out);
  } else {
    attn_fwd_self<<<dim3(S_LEN / 128, NBH), dim3(256), 0, stream>>>(q, k, v, mask, out);
  }
}

// Round 17
// 154.747 us; speedup vs baseline: 1.3285x; 1.0109x over previous
//
#include <hip/hip_runtime.h>

// BaseAttention: B=2 H=16 S=2048 D=64, fp32 in/out.
// Round 21: 8-wave / 128-q-row blocks on the r20 pipeline (grid 1024 -> 512).
//   r20 WIN (77->65.1us): wave-contiguous mask layout killed the 4KB-stride
//   request amplification -- request RATE was the hidden axis. Next invariant
//   of the same class: block-count redundancy. Each bh's KV image re-staged by
//   32 qt-blocks (537MB L2-side); 1024 blocks x 32 barrier intervals.
//   This round: 512-thread blocks, 8 waves = (qh 0..3) x (kh 0..1), 128 q
//   rows/block. Waves/CU unchanged (2 blocks x 8 = 16), LDS unchanged
//   (2x16KB + 512B lb), per-wave work shape identical to r20. Staging
//   redundancy + barrier instances HALVE. Staging 2 segs/wave: entry
//   vmcnt(2) (same validated queue shape: exit issues [ml x2, stage x2];
//   newest 2 = stage(kt+1) stay in flight). Mask base generalizes to
//   block id 4*qt+qh (same r20 slab layout, unchanged prep). Epilogue:
//   kh=1 waves write oT to stride-64 f32 alias over sbuf (32KB exact),
//   l to separate lb[128]; one-time bank conflicts acceptable.
//   Unchanged from r20 (validated at 65.1us): frag image + fused prep,
//   counted entry vmcnt, exit lgkmcnt(0)+barrier+[masks,stages], XCD
//   swizzle, ones-A MFMA l, setprio, Q pre-scaled 0.125*log2e, pkrtz f16 P.
//   Kill: attn >= 66us => redundancy axis dead; final lever = bit-packed
//   masks, else structural floor.

#define S_LEN 2048
#define D_DIM 64
#define N_KT 32
#define NBH 32
#define TILE_SEGS 16
#define TILE_SHORTS 8192                 // 16 KB: [K frags 4096][V frags 4096]
#define SEG_U32 256                      // 1024 B per seg (64 lanes x 16 B)

typedef __attribute__((ext_vector_type(8))) short bf16x8;
typedef __attribute__((ext_vector_type(16))) float f32x16;
typedef __attribute__((ext_vector_type(2))) __fp16 fp16x2;
typedef unsigned int u32;

#define C1 0.180336880111121f    // 0.125 * log2(e)
#define CM (-14426.9504088896f)  // -10000 * log2(e)  (fallback kernel only)

static __device__ __forceinline__ unsigned short f2bf(float f) {
  union { float f; unsigned u; } x; x.f = f;
  return (unsigned short)((x.u + 0x8000u) >> 16);
}
static __device__ __forceinline__ unsigned packbf(float lo, float hi) {
  union { float f; unsigned u; } a, b; a.f = lo; b.f = hi;
  return ((a.u + 0x8000u) >> 16) | ((b.u + 0x8000u) & 0xffff0000u);
}
static __device__ __forceinline__ f32x16 zero16() {
  f32x16 z;
#pragma unroll
  for (int i = 0; i < 16; ++i) z[i] = 0.f;
  return z;
}
static __device__ __forceinline__ void dma16(const u32* g, u32* l) {
  __builtin_amdgcn_global_load_lds(
      (const __attribute__((address_space(1))) u32*)g,
      (__attribute__((address_space(3))) u32*)l, 16, 0, 0);
}
static __device__ __forceinline__ unsigned pkh(float lo, float hi) {
  union { fp16x2 h; unsigned u; } x;
  x.h = __builtin_amdgcn_cvt_pkrtz(lo, hi);
  return x.u;
}

// ---- fused pre-pass: blocks [0,1024): K,V frag image; [1024,3072): mask ----
// (r20-validated verbatim: KV frag image + wave-contiguous mask layout)
__global__ __launch_bounds__(256) void prep_fused(
    const float* __restrict__ k, const float* __restrict__ v,
    const int* __restrict__ mask, unsigned short* __restrict__ kvws,
    u32* __restrict__ mw) {
  __shared__ unsigned short Kr[64 * 72];
  __shared__ unsigned short Vr[64 * 72];
  const int blk = blockIdx.x;
  const int t = threadIdx.x;
  if (blk < N_KT * NBH) {
    const int kt = blk & 31, bh = blk >> 5;
    const size_t goff = (size_t)bh * (S_LEN * D_DIM) + (size_t)kt * 64 * D_DIM;
    const float4* kg = (const float4*)(k + goff);
    const float4* vg = (const float4*)(v + goff);
#pragma unroll
    for (int j = 0; j < 4; ++j) {
      const int i = t + j * 256;
      const int row = i >> 4, c4 = i & 15;  // row = key, c4 = d-group
      const float4 x = kg[i];
      ushort4 w;
      w.x = f2bf(x.x); w.y = f2bf(x.y); w.z = f2bf(x.z); w.w = f2bf(x.w);
      *(ushort4*)&Kr[row * 72 + c4 * 4] = w;
      const float4 y = vg[i];
      const unsigned p01 = pkh(y.x, y.y), p23 = pkh(y.z, y.w);
      uint2 vv; vv.x = p01; vv.y = p23;
      *(uint2*)&Vr[row * 72 + c4 * 4] = vv;
    }
    __syncthreads();
    uint4* img = (uint4*)(kvws + (size_t)(bh * N_KT + kt) * TILE_SHORTS);
    for (int c = t; c < 512; c += 256) {
      const int col = c & 31, hlc = (c >> 5) & 1, ks = (c >> 6) & 3, khc = c >> 8;
      img[c] = *(const uint4*)&Kr[(khc * 32 + col) * 72 + ks * 16 + hlc * 8];
    }
    for (int c = t; c < 512; c += 256) {
      const int col = c & 31, b = (c >> 5) & 1, hlc = (c >> 6) & 1, kcHi = c >> 7;
      const int d = b * 32 + col, kk = (2 * kcHi + hlc) * 8;
      union { unsigned short s[8]; uint4 u; } o;
#pragma unroll
      for (int jj = 0; jj < 8; ++jj) o.s[jj] = Vr[(kk + jj) * 72 + d];
      img[512 + c] = o.u;
    }
  } else {
    // wave-contiguous mask layout (r20-validated):
    //   uint4 o = (rowblk64*2 + qh')*8192 + kt*256 + kh*128 + hl*64 + col*2 + i4
    // word j of uint4 masks keys base+{0,1},{2,3},{8,9},{10,11},
    // base = kt*64 + 32*kh + 16*i4 + 4*hl; mask==0 -> keep (0xFFFF).
    const int o = (blk - N_KT * NBH) * 256 + t;  // 524288 total
    const int i4 = o & 1;
    const int col = (o >> 1) & 31;
    const int hl = (o >> 6) & 1;
    const int kh = (o >> 7) & 1;
    const int kt = (o >> 8) & 31;
    const int qh = (o >> 13) & 1;
    const int qt = o >> 14;
    const int row = qt * 64 + qh * 32 + col;
    const int base_key = kt * 64 + 32 * kh + 16 * i4 + 4 * hl;
    const int* mr = mask + (size_t)row * S_LEN;
    const int4 a = *(const int4*)(mr + base_key);
    const int4 b = *(const int4*)(mr + base_key + 8);
    uint4 w;
    w.x = (a.x == 0 ? 0x0000FFFFu : 0u) | (a.y == 0 ? 0xFFFF0000u : 0u);
    w.y = (a.z == 0 ? 0x0000FFFFu : 0u) | (a.w == 0 ? 0xFFFF0000u : 0u);
    w.z = (b.x == 0 ? 0x0000FFFFu : 0u) | (b.y == 0 ? 0xFFFF0000u : 0u);
    w.w = (b.z == 0 ? 0x0000FFFFu : 0u) | (b.w == 0 ? 0xFFFF0000u : 0u);
    ((uint4*)mw)[o] = w;
  }
}

// ---- main: 8-wave 128-q-row blocks, r20 pipeline ----
__global__ __launch_bounds__(512, 2) void attn_fwd(
    const float* __restrict__ q, const unsigned short* __restrict__ kvws,
    const u32* __restrict__ mw, float* __restrict__ out) {
  // XCD swizzle: 512 blocks, lin%8 = XCD. XCD x hosts bh in [4x,4x+4).
  const int lin = blockIdx.x + 16 * blockIdx.y;
  const int xcd = lin & 7;
  const int wk = lin >> 3;           // 0..63
  const int qt = wk & 15;            // 128-row q block, 0..15
  const int bh = xcd * 4 + (wk >> 4);
  const size_t hoff = (size_t)bh * (S_LEN * D_DIM);

  __shared__ unsigned short sbuf[2][TILE_SHORTS];  // 2 x 16 KB
  __shared__ float lb[128];                        // epilogue l exchange

  const int t = threadIdx.x;
  const int wave = t >> 6;           // 0..7
  const int lane = t & 63;
  const int col = lane & 31;
  const int hl = lane >> 5;
  const int qh = wave >> 1;          // q quarter: rows qh*32..qh*32+31
  const int kh = wave & 1;           // key half of each tile
  const int qg = qt * 128 + qh * 32 + col;

  // Q^T B-fragments, PRE-SCALED by C1
  bf16x8 bQ[4];
  {
    const float* qrow = q + hoff + (size_t)qg * D_DIM;
#pragma unroll
    for (int ks = 0; ks < 4; ++ks) {
      const float4 x0 = *(const float4*)(qrow + ks * 16 + hl * 8);
      const float4 x1 = *(const float4*)(qrow + ks * 16 + hl * 8 + 4);
      union { bf16x8 v; unsigned d[4]; } u;
      u.d[0] = packbf(x0.x * C1, x0.y * C1);
      u.d[1] = packbf(x0.z * C1, x0.w * C1);
      u.d[2] = packbf(x1.x * C1, x1.y * C1);
      u.d[3] = packbf(x1.z * C1, x1.w * C1);
      bQ[ks] = u.v;
    }
  }

  // ones A-fragment (f16 1.0) for the l row-sum MFMA
  bf16x8 onesA;
  {
    union { bf16x8 v; unsigned d[4]; } u;
    u.d[0] = u.d[1] = u.d[2] = u.d[3] = 0x3C003C00u;
    onesA = u.v;
  }

  f32x16 oT0 = zero16(), oT1 = zero16(), oL = zero16();
  // mask base: rowblk64 = 2qt + (qh>>1), qh' = qh&1 => block id = 4*qt + qh.
  const uint4* mbase = (const uint4*)mw + (size_t)(4 * qt + qh) * 8192 +
                       kh * 128 + hl * 64 + col * 2;
  const u32* img = (const u32*)(kvws + (size_t)bh * N_KT * TILE_SHORTS);
  const int seg0 = wave * 2;  // this wave's 2 segments of each 16-seg tile

  uint4 mq0, mq1;
  // prologue vmem order (per wave): ml(0) x2, stage(0) x2, stage(1) x2.
  {
    const uint4* mp = mbase;  // kt = 0
    asm volatile("global_load_dwordx4 %0, %2, off\n\t"
                 "global_load_dwordx4 %1, %3, off"
                 : "=&v"(mq0), "=&v"(mq1)
                 : "v"(mp), "v"(mp + 1)
                 : "memory");
  }
#pragma unroll
  for (int s = 0; s < 2; ++s)
    dma16(img + (size_t)(seg0 + s) * SEG_U32 + lane * 4,
          (u32*)&sbuf[0][0] + (seg0 + s) * SEG_U32);
#pragma unroll
  for (int s = 0; s < 2; ++s)
    dma16(img + (size_t)(TILE_SEGS + seg0 + s) * SEG_U32 + lane * 4,
          (u32*)&sbuf[1][0] + (seg0 + s) * SEG_U32);

  for (int kt = 0; kt < N_KT; ++kt) {
    const int p = kt & 1;
    // entry: own stage(kt)+ml(kt) complete; stage(kt+1) x2 stays in flight
    if (kt < N_KT - 1) {
      asm volatile("s_waitcnt vmcnt(2)" ::: "memory");
    } else {
      asm volatile("s_waitcnt vmcnt(0)" ::: "memory");
    }
    __builtin_amdgcn_s_barrier();
    __builtin_amdgcn_sched_barrier(0);

    const unsigned short* Ksb = &sbuf[p][0];
    const unsigned short* Vtb = &sbuf[p][4096];
    const u32 mwv[8] = {mq0.x, mq0.y, mq0.z, mq0.w,
                        mq1.x, mq1.y, mq1.z, mq1.w};

    // S^T = K Q^T : this wave's 32-key half x K=64 (pre-scaled via Q)
    f32x16 sT = zero16();
    __builtin_amdgcn_s_setprio(1);
#pragma unroll
    for (int ks = 0; ks < 4; ++ks) {
      const bf16x8 aK =
          *(const bf16x8*)&Ksb[kh * 2048 + ks * 512 + hl * 256 + col * 8];
      sT = __builtin_amdgcn_mfma_f32_32x32x16_bf16(aK, bQ[ks], sT, 0, 0, 0);
    }
    __builtin_amdgcn_s_setprio(0);

    // p = exp2(s), pack f16 (pkrtz), mask with AND-words
    unsigned pw[8];
#pragma unroll
    for (int g2 = 0; g2 < 4; ++g2) {
      const float e0 = __builtin_amdgcn_exp2f(sT[g2 * 4 + 0]);
      const float e1 = __builtin_amdgcn_exp2f(sT[g2 * 4 + 1]);
      const float e2 = __builtin_amdgcn_exp2f(sT[g2 * 4 + 2]);
      const float e3 = __builtin_amdgcn_exp2f(sT[g2 * 4 + 3]);
      pw[g2 * 2 + 0] = pkh(e0, e1) & mwv[g2 * 2 + 0];
      pw[g2 * 2 + 1] = pkh(e2, e3) & mwv[g2 * 2 + 1];
    }

    // O^T += Vt * P^T ; l += ones * P^T (exact row-sum of masked P)
    __builtin_amdgcn_s_setprio(1);
#pragma unroll
    for (int ks2 = 0; ks2 < 2; ++ks2) {
      const unsigned d0 = pw[4 * ks2 + 0], d1 = pw[4 * ks2 + 1];
      const unsigned d2 = pw[4 * ks2 + 2], d3 = pw[4 * ks2 + 3];
      const unsigned s0 = hl ? d0 : d2;
      const unsigned s1 = hl ? d1 : d3;
      const unsigned r0 = (unsigned)__shfl_xor((int)s0, 32);
      const unsigned r1 = (unsigned)__shfl_xor((int)s1, 32);
      union { bf16x8 v; unsigned d[4]; } pf;
      pf.d[0] = hl ? r0 : d0;
      pf.d[1] = hl ? r1 : d1;
      pf.d[2] = hl ? d2 : r0;
      pf.d[3] = hl ? d3 : r1;
      const int kcHi = kh * 2 + ks2;
      const bf16x8 aV0 =
          *(const bf16x8*)&Vtb[kcHi * 1024 + hl * 512 + 0 * 256 + col * 8];
      const bf16x8 aV1 =
          *(const bf16x8*)&Vtb[kcHi * 1024 + hl * 512 + 1 * 256 + col * 8];
      oT0 = __builtin_amdgcn_mfma_f32_32x32x16_f16(aV0, pf.v, oT0, 0, 0, 0);
      oT1 = __builtin_amdgcn_mfma_f32_32x32x16_f16(aV1, pf.v, oT1, 0, 0, 0);
      oL = __builtin_amdgcn_mfma_f32_32x32x16_f16(onesA, pf.v, oL, 0, 0, 0);
    }
    __builtin_amdgcn_s_setprio(0);

    // exit: reads of buf[p] done -> allow re-staging it; masks BEFORE dmas
    if (kt < N_KT - 1) {
      asm volatile("s_waitcnt lgkmcnt(0)" ::: "memory");
      __builtin_amdgcn_s_barrier();
      __builtin_amdgcn_sched_barrier(0);
      {
        const uint4* mp = mbase + (size_t)(kt + 1) * 256;
        asm volatile("global_load_dwordx4 %0, %2, off\n\t"
                     "global_load_dwordx4 %1, %3, off"
                     : "=&v"(mq0), "=&v"(mq1)
                     : "v"(mp), "v"(mp + 1)
                     : "memory");
      }
      if (kt < N_KT - 2) {
        const u32* g = img + (size_t)(kt + 2) * (TILE_SEGS * SEG_U32);
#pragma unroll
        for (int s = 0; s < 2; ++s)
          dma16(g + (size_t)(seg0 + s) * SEG_U32 + lane * 4,
                (u32*)&sbuf[p][0] + (seg0 + s) * SEG_U32);
      }
    }
  }

  // ---- cross-wave key-half reduction: stride-64 f32 alias over sbuf ----
  __syncthreads();  // all tile reads done; sbuf free to alias (32768 B exact)
  {
    float* xb = (float*)&sbuf[0][0];                 // 128 rows x 64 floats
    float* xr = xb + (size_t)(qh * 32 + col) * 64;
    if (kh) {
#pragma unroll
      for (int rg = 0; rg < 4; ++rg) {
        float4 w0, w1;
        w0.x = oT0[rg * 4 + 0]; w0.y = oT0[rg * 4 + 1];
        w0.z = oT0[rg * 4 + 2]; w0.w = oT0[rg * 4 + 3];
        w1.x = oT1[rg * 4 + 0]; w1.y = oT1[rg * 4 + 1];
        w1.z = oT1[rg * 4 + 2]; w1.w = oT1[rg * 4 + 3];
        *(float4*)(xr + 8 * rg + 4 * hl) = w0;
        *(float4*)(xr + 32 + 8 * rg + 4 * hl) = w1;
      }
      if (!hl) lb[qh * 32 + col] = oL[0];  // every C row of ones*P^T = l(q=col)
    }
    __syncthreads();
    if (!kh) {
      const float inv = 1.0f / (oL[0] + lb[qh * 32 + col]);
      float* orow = out + hoff + (size_t)qg * D_DIM;
#pragma unroll
      for (int rg = 0; rg < 4; ++rg) {
        const float4 a0 = *(const float4*)(xr + 8 * rg + 4 * hl);
        const float4 a1 = *(const float4*)(xr + 32 + 8 * rg + 4 * hl);
        float4 w0, w1;
        w0.x = (oT0[rg * 4 + 0] + a0.x) * inv;
        w0.y = (oT0[rg * 4 + 1] + a0.y) * inv;
        w0.z = (oT0[rg * 4 + 2] + a0.z) * inv;
        w0.w = (oT0[rg * 4 + 3] + a0.w) * inv;
        w1.x = (oT1[rg * 4 + 0] + a1.x) * inv;
        w1.y = (oT1[rg * 4 + 1] + a1.y) * inv;
        w1.z = (oT1[rg * 4 + 2] + a1.z) * inv;
        w1.w = (oT1[rg * 4 + 3] + a1.w) * inv;
        *(float4*)(orow + 8 * rg + 4 * hl) = w0;
        *(float4*)(orow + 32 + 8 * rg + 4 * hl) = w1;
      }
    }
  }
}

// ---- fallback (round-4 kernel, self-staging) if ws is too small ----
#define LDK 72
#define LDV 72
__global__ __launch_bounds__(256, 2) void attn_fwd_self(
    const float* __restrict__ q, const float* __restrict__ k,
    const float* __restrict__ v, const int* __restrict__ mask,
    float* __restrict__ out) {
  const int qt = blockIdx.x;
  const int bh = blockIdx.y;
  const size_t hoff = (size_t)bh * (S_LEN * D_DIM);
  __shared__ unsigned short Ks[64 * LDK];
  __shared__ unsigned short Vt[64 * LDV];
  const int t = threadIdx.x;
  const int wave = t >> 6;
  const int lane = t & 63;
  const int col = lane & 31;
  const int hl = lane >> 5;
  const int sw = col >> 2;
  const int qg = qt * 128 + wave * 32 + col;
  bf16x8 bQ[4];
  {
    const float* qrow = q + hoff + (size_t)qg * D_DIM;
#pragma unroll
    for (int ks = 0; ks < 4; ++ks) {
      const float4 x0 = *(const float4*)(qrow + ks * 16 + hl * 8);
      const float4 x1 = *(const float4*)(qrow + ks * 16 + hl * 8 + 4);
      union { bf16x8 v; unsigned d[4]; } u;
      u.d[0] = packbf(x0.x, x0.y);
      u.d[1] = packbf(x0.z, x0.w);
      u.d[2] = packbf(x1.x, x1.y);
      u.d[3] = packbf(x1.z, x1.w);
      bQ[ks] = u.v;
    }
  }
  float4 pk[4], pv[4];
  {
    const float4* kg = (const float4*)(k + hoff);
    const float4* vg = (const float4*)(v + hoff);
#pragma unroll
    for (int j = 0; j < 4; ++j) { pk[j] = kg[t + j * 256]; pv[j] = vg[t + j * 256]; }
  }
  f32x16 oT0 = zero16(), oT1 = zero16();
  float lacc = 0.f;
  const int* mrow = mask + (size_t)qg * S_LEN;
  for (int kt = 0; kt < N_KT; ++kt) {
    __syncthreads();
#pragma unroll
    for (int j = 0; j < 4; ++j) {
      const int i = t + j * 256;
      const int row = i >> 4, c4 = i & 15;
      ushort4 w;
      w.x = f2bf(pk[j].x); w.y = f2bf(pk[j].y);
      w.z = f2bf(pk[j].z); w.w = f2bf(pk[j].w);
      *(ushort4*)&Ks[row * LDK + c4 * 4] = w;
      const int swc = 8 * (((row >> 3) + c4) & 7) + (row & 7);
      Vt[(4 * c4 + 0) * LDV + swc] = f2bf(pv[j].x);
      Vt[(4 * c4 + 1) * LDV + swc] = f2bf(pv[j].y);
      Vt[(4 * c4 + 2) * LDV + swc] = f2bf(pv[j].z);
      Vt[(4 * c4 + 3) * LDV + swc] = f2bf(pv[j].w);
    }
    __syncthreads();
    if (kt + 1 < N_KT) {
      const float4* kg = (const float4*)(k + hoff + (size_t)(kt + 1) * 64 * D_DIM);
      const float4* vg = (const float4*)(v + hoff + (size_t)(kt + 1) * 64 * D_DIM);
#pragma unroll
      for (int j = 0; j < 4; ++j) { pk[j] = kg[t + j * 256]; pv[j] = vg[t + j * 256]; }
    }
    int4 mq[2][4];
#pragma unroll
    for (int kb = 0; kb < 2; ++kb)
#pragma unroll
      for (int g = 0; g < 4; ++g)
        mq[kb][g] = *(const int4*)(mrow + kt * 64 + kb * 32 + g * 8 + hl * 4);
    f32x16 sT0 = zero16(), sT1 = zero16();
#pragma unroll
    for (int ks = 0; ks < 4; ++ks) {
      const bf16x8 aK0 = *(const bf16x8*)&Ks[col * LDK + ks * 16 + hl * 8];
      const bf16x8 aK1 = *(const bf16x8*)&Ks[(32 + col) * LDK + ks * 16 + hl * 8];
      sT0 = __builtin_amdgcn_mfma_f32_32x32x16_bf16(aK0, bQ[ks], sT0, 0, 0, 0);
      sT1 = __builtin_amdgcn_mfma_f32_32x32x16_bf16(aK1, bQ[ks], sT1, 0, 0, 0);
    }
    unsigned pw[2][8];
#pragma unroll
    for (int kb = 0; kb < 2; ++kb) {
      const f32x16 sT = kb ? sT1 : sT0;
      float e[16];
#pragma unroll
      for (int g = 0; g < 4; ++g) {
        const int4 mv = mq[kb][g];
        const int* mvp = &mv.x;
#pragma unroll
        for (int r3 = 0; r3 < 4; ++r3) {
          const int reg = g * 4 + r3;
          const float bias = mvp[r3] ? CM : 0.0f;
          const float ev = __builtin_amdgcn_exp2f(fmaf(sT[reg], C1, bias));
          e[reg] = ev;
          lacc += ev;
        }
        pw[kb][g * 2 + 0] = packbf(e[g * 4 + 0], e[g * 4 + 1]);
        pw[kb][g * 2 + 1] = packbf(e[g * 4 + 2], e[g * 4 + 3]);
      }
    }
#pragma unroll
    for (int ks = 0; ks < 4; ++ks) {
      const int kb = ks >> 1, h = ks & 1;
      const unsigned d0 = pw[kb][4 * h + 0], d1 = pw[kb][4 * h + 1];
      const unsigned d2 = pw[kb][4 * h + 2], d3 = pw[kb][4 * h + 3];
      const unsigned s0 = hl ? d0 : d2;
      const unsigned s1 = hl ? d1 : d3;
      const unsigned r0 = (unsigned)__shfl_xor((int)s0, 32);
      const unsigned r1 = (unsigned)__shfl_xor((int)s1, 32);
      union { bf16x8 v; unsigned d[4]; } pf;
      pf.d[0] = hl ? r0 : d0;
      pf.d[1] = hl ? r1 : d1;
      pf.d[2] = hl ? d2 : r0;
      pf.d[3] = hl ? d3 : r1;
      const int cpr = 8 * (((2 * ks + hl) + sw) & 7);
      const bf16x8 aV0 = *(const bf16x8*)&Vt[col * LDV + cpr];
      const bf16x8 aV1 = *(const bf16x8*)&Vt[(32 + col) * LDV + cpr];
      oT0 = __builtin_amdgcn_mfma_f32_32x32x16_bf16(aV0, pf.v, oT0, 0, 0, 0);
      oT1 = __builtin_amdgcn_mfma_f32_32x32x16_bf16(aV1, pf.v, oT1, 0, 0, 0);
    }
  }
  const float ltot = lacc + __shfl_xor(lacc, 32);
  const float inv = 1.0f / ltot;
  float* orow = out + hoff + (size_t)qg * D_DIM;
#pragma unroll
  for (int rg = 0; rg < 4; ++rg) {
    float4 w0, w1;
    w0.x = oT0[rg * 4 + 0] * inv; w0.y = oT0[rg * 4 + 1] * inv;
    w0.z = oT0[rg * 4 + 2] * inv; w0.w = oT0[rg * 4 + 3] * inv;
    w1.x = oT1[rg * 4 + 0] * inv; w1.y = oT1[rg * 4 + 1] * inv;
    w1.z = oT1[rg * 4 + 2] * inv; w1.w = oT1[rg * 4 + 3] * inv;
    *(float4*)(orow + 8 * rg + 4 * hl) = w0;
    *(float4*)(orow + 32 + 8 * rg + 4 * hl) = w1;
  }
}

extern "C" void kernel_launch(void* const* d_in, const int* in_sizes, int n_in,
                              void* d_out, int out_size, void* d_ws, size_t ws_size,
                              hipStream_t stream) {
  const float* q = (const float*)d_in[0];
  const float* k = (const float*)d_in[1];
  const float* v = (const float*)d_in[2];
  const int* mask = (const int*)d_in[3];
  float* out = (float*)d_out;

  const size_t kv_shorts = (size_t)NBH * N_KT * TILE_SHORTS;
  const size_t mw_words = (size_t)S_LEN * 2 * N_KT * 16;  // u32 count (8 MB)
  const size_t need = kv_shorts * sizeof(unsigned short) + mw_words * 4;

  if (ws_size >= need) {
    unsigned short* kvws = (unsigned short*)d_ws;
    u32* mwp = (u32*)(kvws + kv_shorts);
    prep_fused<<<dim3(N_KT * NBH + (S_LEN * 2 * N_KT * 4) / 256), dim3(256), 0,
                 stream>>>(k, v, mask, kvws, mwp);
    attn_fwd<<<dim3(S_LEN / 128, NBH), dim3(512), 0, stream>>>(q, kvws, mwp, out);
  } else {
    attn_fwd_self<<<dim3(S_LEN / 128, NBH), dim3(256), 0, stream>>>(q, k, v, mask, out);
  }
}

// Round 19
// 149.916 us; speedup vs baseline: 1.3714x; 1.0322x over previous
//
#include <hip/hip_runtime.h>

// BaseAttention: B=2 H=16 S=2048 D=64, fp32 in/out.
// Round 22 (resubmit; container-infra failure, never measured).
// Fix epilogue 32-way bank conflict (XOR slot swizzle) on r21.
//   r21 WIN (65.1->62.0us attn, total 154.7 session best): 8-wave 128-q-row
//   blocks halved staging redundancy (FETCH 66->53MB). New counter flag:
//   SQ_LDS_BANK_CONFLICT 0 -> 1.9M -- epilogue alias stride-64 floats =
//   256B rows => all 32 lanes same bank (32-way, write AND read).
//   Fix: slot swizzle s' = s ^ (row & 15) (bijective per row; <=2 lanes/bank
//   = free per m136). Same swizzle both sides (row identical for writer
//   kh=1 and reader kh=0). Everything else frozen from r21:
//   8 waves = (qh 0..3) x (kh 0..1), 2 segs/wave staging, entry vmcnt(2),
//   exit lgkmcnt(0)+barrier+[masks,stages], wave-contiguous mask slab (r20),
//   frag image + fused prep, XCD swizzle, ones-A MFMA l, setprio,
//   Q pre-scaled 0.125*log2e, pkrtz f16 P.
//   Kill: delta < 1.5us => epilogue off critical path; all counters clean =>
//   structural floor, declare next round.

#define S_LEN 2048
#define D_DIM 64
#define N_KT 32
#define NBH 32
#define TILE_SEGS 16
#define TILE_SHORTS 8192                 // 16 KB: [K frags 4096][V frags 4096]
#define SEG_U32 256                      // 1024 B per seg (64 lanes x 16 B)

typedef __attribute__((ext_vector_type(8))) short bf16x8;
typedef __attribute__((ext_vector_type(16))) float f32x16;
typedef __attribute__((ext_vector_type(2))) __fp16 fp16x2;
typedef unsigned int u32;

#define C1 0.180336880111121f    // 0.125 * log2(e)
#define CM (-14426.9504088896f)  // -10000 * log2(e)  (fallback kernel only)

static __device__ __forceinline__ unsigned short f2bf(float f) {
  union { float f; unsigned u; } x; x.f = f;
  return (unsigned short)((x.u + 0x8000u) >> 16);
}
static __device__ __forceinline__ unsigned packbf(float lo, float hi) {
  union { float f; unsigned u; } a, b; a.f = lo; b.f = hi;
  return ((a.u + 0x8000u) >> 16) | ((b.u + 0x8000u) & 0xffff0000u);
}
static __device__ __forceinline__ f32x16 zero16() {
  f32x16 z;
#pragma unroll
  for (int i = 0; i < 16; ++i) z[i] = 0.f;
  return z;
}
static __device__ __forceinline__ void dma16(const u32* g, u32* l) {
  __builtin_amdgcn_global_load_lds(
      (const __attribute__((address_space(1))) u32*)g,
      (__attribute__((address_space(3))) u32*)l, 16, 0, 0);
}
static __device__ __forceinline__ unsigned pkh(float lo, float hi) {
  union { fp16x2 h; unsigned u; } x;
  x.h = __builtin_amdgcn_cvt_pkrtz(lo, hi);
  return x.u;
}

// ---- fused pre-pass: blocks [0,1024): K,V frag image; [1024,3072): mask ----
// (r20/r21-validated verbatim)
__global__ __launch_bounds__(256) void prep_fused(
    const float* __restrict__ k, const float* __restrict__ v,
    const int* __restrict__ mask, unsigned short* __restrict__ kvws,
    u32* __restrict__ mw) {
  __shared__ unsigned short Kr[64 * 72];
  __shared__ unsigned short Vr[64 * 72];
  const int blk = blockIdx.x;
  const int t = threadIdx.x;
  if (blk < N_KT * NBH) {
    const int kt = blk & 31, bh = blk >> 5;
    const size_t goff = (size_t)bh * (S_LEN * D_DIM) + (size_t)kt * 64 * D_DIM;
    const float4* kg = (const float4*)(k + goff);
    const float4* vg = (const float4*)(v + goff);
#pragma unroll
    for (int j = 0; j < 4; ++j) {
      const int i = t + j * 256;
      const int row = i >> 4, c4 = i & 15;  // row = key, c4 = d-group
      const float4 x = kg[i];
      ushort4 w;
      w.x = f2bf(x.x); w.y = f2bf(x.y); w.z = f2bf(x.z); w.w = f2bf(x.w);
      *(ushort4*)&Kr[row * 72 + c4 * 4] = w;
      const float4 y = vg[i];
      const unsigned p01 = pkh(y.x, y.y), p23 = pkh(y.z, y.w);
      uint2 vv; vv.x = p01; vv.y = p23;
      *(uint2*)&Vr[row * 72 + c4 * 4] = vv;
    }
    __syncthreads();
    uint4* img = (uint4*)(kvws + (size_t)(bh * N_KT + kt) * TILE_SHORTS);
    for (int c = t; c < 512; c += 256) {
      const int col = c & 31, hlc = (c >> 5) & 1, ks = (c >> 6) & 3, khc = c >> 8;
      img[c] = *(const uint4*)&Kr[(khc * 32 + col) * 72 + ks * 16 + hlc * 8];
    }
    for (int c = t; c < 512; c += 256) {
      const int col = c & 31, b = (c >> 5) & 1, hlc = (c >> 6) & 1, kcHi = c >> 7;
      const int d = b * 32 + col, kk = (2 * kcHi + hlc) * 8;
      union { unsigned short s[8]; uint4 u; } o;
#pragma unroll
      for (int jj = 0; jj < 8; ++jj) o.s[jj] = Vr[(kk + jj) * 72 + d];
      img[512 + c] = o.u;
    }
  } else {
    // wave-contiguous mask layout (r20-validated):
    //   uint4 o = (qt64*2 + qh')*8192 + kt*256 + kh*128 + hl*64 + col*2 + i4
    // word j of uint4 masks keys base+{0,1},{2,3},{8,9},{10,11},
    // base = kt*64 + 32*kh + 16*i4 + 4*hl; mask==0 -> keep (0xFFFF).
    const int o = (blk - N_KT * NBH) * 256 + t;  // 524288 total
    const int i4 = o & 1;
    const int col = (o >> 1) & 31;
    const int hl = (o >> 6) & 1;
    const int kh = (o >> 7) & 1;
    const int kt = (o >> 8) & 31;
    const int qh = (o >> 13) & 1;
    const int qt = o >> 14;
    const int row = qt * 64 + qh * 32 + col;
    const int base_key = kt * 64 + 32 * kh + 16 * i4 + 4 * hl;
    const int* mr = mask + (size_t)row * S_LEN;
    const int4 a = *(const int4*)(mr + base_key);
    const int4 b = *(const int4*)(mr + base_key + 8);
    uint4 w;
    w.x = (a.x == 0 ? 0x0000FFFFu : 0u) | (a.y == 0 ? 0xFFFF0000u : 0u);
    w.y = (a.z == 0 ? 0x0000FFFFu : 0u) | (a.w == 0 ? 0xFFFF0000u : 0u);
    w.z = (b.x == 0 ? 0x0000FFFFu : 0u) | (b.y == 0 ? 0xFFFF0000u : 0u);
    w.w = (b.z == 0 ? 0x0000FFFFu : 0u) | (b.w == 0 ? 0xFFFF0000u : 0u);
    ((uint4*)mw)[o] = w;
  }
}

// ---- main: 8-wave 128-q-row blocks, r21 pipeline, swizzled epilogue ----
__global__ __launch_bounds__(512, 2) void attn_fwd(
    const float* __restrict__ q, const unsigned short* __restrict__ kvws,
    const u32* __restrict__ mw, float* __restrict__ out) {
  // XCD swizzle: 512 blocks, lin%8 = XCD. XCD x hosts bh in [4x,4x+4).
  const int lin = blockIdx.x + 16 * blockIdx.y;
  const int xcd = lin & 7;
  const int wk = lin >> 3;           // 0..63
  const int qt = wk & 15;            // 128-row q block, 0..15
  const int bh = xcd * 4 + (wk >> 4);
  const size_t hoff = (size_t)bh * (S_LEN * D_DIM);

  __shared__ unsigned short sbuf[2][TILE_SHORTS];  // 2 x 16 KB
  __shared__ float lb[128];                        // epilogue l exchange

  const int t = threadIdx.x;
  const int wave = t >> 6;           // 0..7
  const int lane = t & 63;
  const int col = lane & 31;
  const int hl = lane >> 5;
  const int qh = wave >> 1;          // q quarter: rows qh*32..qh*32+31
  const int kh = wave & 1;           // key half of each tile
  const int qg = qt * 128 + qh * 32 + col;

  // Q^T B-fragments, PRE-SCALED by C1
  bf16x8 bQ[4];
  {
    const float* qrow = q + hoff + (size_t)qg * D_DIM;
#pragma unroll
    for (int ks = 0; ks < 4; ++ks) {
      const float4 x0 = *(const float4*)(qrow + ks * 16 + hl * 8);
      const float4 x1 = *(const float4*)(qrow + ks * 16 + hl * 8 + 4);
      union { bf16x8 v; unsigned d[4]; } u;
      u.d[0] = packbf(x0.x * C1, x0.y * C1);
      u.d[1] = packbf(x0.z * C1, x0.w * C1);
      u.d[2] = packbf(x1.x * C1, x1.y * C1);
      u.d[3] = packbf(x1.z * C1, x1.w * C1);
      bQ[ks] = u.v;
    }
  }

  // ones A-fragment (f16 1.0) for the l row-sum MFMA
  bf16x8 onesA;
  {
    union { bf16x8 v; unsigned d[4]; } u;
    u.d[0] = u.d[1] = u.d[2] = u.d[3] = 0x3C003C00u;
    onesA = u.v;
  }

  f32x16 oT0 = zero16(), oT1 = zero16(), oL = zero16();
  // mask base (r20 slab): block id = 4*qt + qh.
  const uint4* mbase = (const uint4*)mw + (size_t)(4 * qt + qh) * 8192 +
                       kh * 128 + hl * 64 + col * 2;
  const u32* img = (const u32*)(kvws + (size_t)bh * N_KT * TILE_SHORTS);
  const int seg0 = wave * 2;  // this wave's 2 segments of each 16-seg tile

  uint4 mq0, mq1;
  // prologue vmem order (per wave): ml(0) x2, stage(0) x2, stage(1) x2.
  {
    const uint4* mp = mbase;  // kt = 0
    asm volatile("global_load_dwordx4 %0, %2, off\n\t"
                 "global_load_dwordx4 %1, %3, off"
                 : "=&v"(mq0), "=&v"(mq1)
                 : "v"(mp), "v"(mp + 1)
                 : "memory");
  }
#pragma unroll
  for (int s = 0; s < 2; ++s)
    dma16(img + (size_t)(seg0 + s) * SEG_U32 + lane * 4,
          (u32*)&sbuf[0][0] + (seg0 + s) * SEG_U32);
#pragma unroll
  for (int s = 0; s < 2; ++s)
    dma16(img + (size_t)(TILE_SEGS + seg0 + s) * SEG_U32 + lane * 4,
          (u32*)&sbuf[1][0] + (seg0 + s) * SEG_U32);

  for (int kt = 0; kt < N_KT; ++kt) {
    const int p = kt & 1;
    // entry: own stage(kt)+ml(kt) complete; stage(kt+1) x2 stays in flight
    if (kt < N_KT - 1) {
      asm volatile("s_waitcnt vmcnt(2)" ::: "memory");
    } else {
      asm volatile("s_waitcnt vmcnt(0)" ::: "memory");
    }
    __builtin_amdgcn_s_barrier();
    __builtin_amdgcn_sched_barrier(0);

    const unsigned short* Ksb = &sbuf[p][0];
    const unsigned short* Vtb = &sbuf[p][4096];
    const u32 mwv[8] = {mq0.x, mq0.y, mq0.z, mq0.w,
                        mq1.x, mq1.y, mq1.z, mq1.w};

    // S^T = K Q^T : this wave's 32-key half x K=64 (pre-scaled via Q)
    f32x16 sT = zero16();
    __builtin_amdgcn_s_setprio(1);
#pragma unroll
    for (int ks = 0; ks < 4; ++ks) {
      const bf16x8 aK =
          *(const bf16x8*)&Ksb[kh * 2048 + ks * 512 + hl * 256 + col * 8];
      sT = __builtin_amdgcn_mfma_f32_32x32x16_bf16(aK, bQ[ks], sT, 0, 0, 0);
    }
    __builtin_amdgcn_s_setprio(0);

    // p = exp2(s), pack f16 (pkrtz), mask with AND-words
    unsigned pw[8];
#pragma unroll
    for (int g2 = 0; g2 < 4; ++g2) {
      const float e0 = __builtin_amdgcn_exp2f(sT[g2 * 4 + 0]);
      const float e1 = __builtin_amdgcn_exp2f(sT[g2 * 4 + 1]);
      const float e2 = __builtin_amdgcn_exp2f(sT[g2 * 4 + 2]);
      const float e3 = __builtin_amdgcn_exp2f(sT[g2 * 4 + 3]);
      pw[g2 * 2 + 0] = pkh(e0, e1) & mwv[g2 * 2 + 0];
      pw[g2 * 2 + 1] = pkh(e2, e3) & mwv[g2 * 2 + 1];
    }

    // O^T += Vt * P^T ; l += ones * P^T (exact row-sum of masked P)
    __builtin_amdgcn_s_setprio(1);
#pragma unroll
    for (int ks2 = 0; ks2 < 2; ++ks2) {
      const unsigned d0 = pw[4 * ks2 + 0], d1 = pw[4 * ks2 + 1];
      const unsigned d2 = pw[4 * ks2 + 2], d3 = pw[4 * ks2 + 3];
      const unsigned s0 = hl ? d0 : d2;
      const unsigned s1 = hl ? d1 : d3;
      const unsigned r0 = (unsigned)__shfl_xor((int)s0, 32);
      const unsigned r1 = (unsigned)__shfl_xor((int)s1, 32);
      union { bf16x8 v; unsigned d[4]; } pf;
      pf.d[0] = hl ? r0 : d0;
      pf.d[1] = hl ? r1 : d1;
      pf.d[2] = hl ? d2 : r0;
      pf.d[3] = hl ? d3 : r1;
      const int kcHi = kh * 2 + ks2;
      const bf16x8 aV0 =
          *(const bf16x8*)&Vtb[kcHi * 1024 + hl * 512 + 0 * 256 + col * 8];
      const bf16x8 aV1 =
          *(const bf16x8*)&Vtb[kcHi * 1024 + hl * 512 + 1 * 256 + col * 8];
      oT0 = __builtin_amdgcn_mfma_f32_32x32x16_f16(aV0, pf.v, oT0, 0, 0, 0);
      oT1 = __builtin_amdgcn_mfma_f32_32x32x16_f16(aV1, pf.v, oT1, 0, 0, 0);
      oL = __builtin_amdgcn_mfma_f32_32x32x16_f16(onesA, pf.v, oL, 0, 0, 0);
    }
    __builtin_amdgcn_s_setprio(0);

    // exit: reads of buf[p] done -> allow re-staging it; masks BEFORE dmas
    if (kt < N_KT - 1) {
      asm volatile("s_waitcnt lgkmcnt(0)" ::: "memory");
      __builtin_amdgcn_s_barrier();
      __builtin_amdgcn_sched_barrier(0);
      {
        const uint4* mp = mbase + (size_t)(kt + 1) * 256;
        asm volatile("global_load_dwordx4 %0, %2, off\n\t"
                     "global_load_dwordx4 %1, %3, off"
                     : "=&v"(mq0), "=&v"(mq1)
                     : "v"(mp), "v"(mp + 1)
                     : "memory");
      }
      if (kt < N_KT - 2) {
        const u32* g = img + (size_t)(kt + 2) * (TILE_SEGS * SEG_U32);
#pragma unroll
        for (int s = 0; s < 2; ++s)
          dma16(g + (size_t)(seg0 + s) * SEG_U32 + lane * 4,
                (u32*)&sbuf[p][0] + (seg0 + s) * SEG_U32);
      }
    }
  }

  // ---- cross-wave key-half reduction: XOR-swizzled f32 alias over sbuf ----
  // xb[128][16] float4 slots; slot s -> s ^ (row & 15): bijective per row,
  // spreads lanes across banks (<=2 lanes/bank = free per m136). Writer
  // (kh=1) and reader (kh=0) share row => identical swizzle both sides.
  __syncthreads();  // all tile reads done; sbuf free to alias (32768 B exact)
  {
    float4* xb4 = (float4*)&sbuf[0][0];              // 128 rows x 16 slots
    const int row = qh * 32 + col;
    const int sw4 = row & 15;
    float4* xr4 = xb4 + (size_t)row * 16;
    if (kh) {
#pragma unroll
      for (int rg = 0; rg < 4; ++rg) {
        float4 w0, w1;
        w0.x = oT0[rg * 4 + 0]; w0.y = oT0[rg * 4 + 1];
        w0.z = oT0[rg * 4 + 2]; w0.w = oT0[rg * 4 + 3];
        w1.x = oT1[rg * 4 + 0]; w1.y = oT1[rg * 4 + 1];
        w1.z = oT1[rg * 4 + 2]; w1.w = oT1[rg * 4 + 3];
        xr4[(2 * rg + hl) ^ sw4] = w0;
        xr4[(8 + 2 * rg + hl) ^ sw4] = w1;
      }
      if (!hl) lb[row] = oL[0];  // every C row of ones*P^T = l(q=col)
    }
    __syncthreads();
    if (!kh) {
      const float inv = 1.0f / (oL[0] + lb[row]);
      float* orow = out + hoff + (size_t)qg * D_DIM;
#pragma unroll
      for (int rg = 0; rg < 4; ++rg) {
        const float4 a0 = xr4[(2 * rg + hl) ^ sw4];
        const float4 a1 = xr4[(8 + 2 * rg + hl) ^ sw4];
        float4 w0, w1;
        w0.x = (oT0[rg * 4 + 0] + a0.x) * inv;
        w0.y = (oT0[rg * 4 + 1] + a0.y) * inv;
        w0.z = (oT0[rg * 4 + 2] + a0.z) * inv;
        w0.w = (oT0[rg * 4 + 3] + a0.w) * inv;
        w1.x = (oT1[rg * 4 + 0] + a1.x) * inv;
        w1.y = (oT1[rg * 4 + 1] + a1.y) * inv;
        w1.z = (oT1[rg * 4 + 2] + a1.z) * inv;
        w1.w = (oT1[rg * 4 + 3] + a1.w) * inv;
        *(float4*)(orow + 8 * rg + 4 * hl) = w0;
        *(float4*)(orow + 32 + 8 * rg + 4 * hl) = w1;
      }
    }
  }
}

// ---- fallback (round-4 kernel, self-staging) if ws is too small ----
#define LDK 72
#define LDV 72
__global__ __launch_bounds__(256, 2) void attn_fwd_self(
    const float* __restrict__ q, const float* __restrict__ k,
    const float* __restrict__ v, const int* __restrict__ mask,
    float* __restrict__ out) {
  const int qt = blockIdx.x;
  const int bh = blockIdx.y;
  const size_t hoff = (size_t)bh * (S_LEN * D_DIM);
  __shared__ unsigned short Ks[64 * LDK];
  __shared__ unsigned short Vt[64 * LDV];
  const int t = threadIdx.x;
  const int wave = t >> 6;
  const int lane = t & 63;
  const int col = lane & 31;
  const int hl = lane >> 5;
  const int sw = col >> 2;
  const int qg = qt * 128 + wave * 32 + col;
  bf16x8 bQ[4];
  {
    const float* qrow = q + hoff + (size_t)qg * D_DIM;
#pragma unroll
    for (int ks = 0; ks < 4; ++ks) {
      const float4 x0 = *(const float4*)(qrow + ks * 16 + hl * 8);
      const float4 x1 = *(const float4*)(qrow + ks * 16 + hl * 8 + 4);
      union { bf16x8 v; unsigned d[4]; } u;
      u.d[0] = packbf(x0.x, x0.y);
      u.d[1] = packbf(x0.z, x0.w);
      u.d[2] = packbf(x1.x, x1.y);
      u.d[3] = packbf(x1.z, x1.w);
      bQ[ks] = u.v;
    }
  }
  float4 pk[4], pv[4];
  {
    const float4* kg = (const float4*)(k + hoff);
    const float4* vg = (const float4*)(v + hoff);
#pragma unroll
    for (int j = 0; j < 4; ++j) { pk[j] = kg[t + j * 256]; pv[j] = vg[t + j * 256]; }
  }
  f32x16 oT0 = zero16(), oT1 = zero16();
  float lacc = 0.f;
  const int* mrow = mask + (size_t)qg * S_LEN;
  for (int kt = 0; kt < N_KT; ++kt) {
    __syncthreads();
#pragma unroll
    for (int j = 0; j < 4; ++j) {
      const int i = t + j * 256;
      const int row = i >> 4, c4 = i & 15;
      ushort4 w;
      w.x = f2bf(pk[j].x); w.y = f2bf(pk[j].y);
      w.z = f2bf(pk[j].z); w.w = f2bf(pk[j].w);
      *(ushort4*)&Ks[row * LDK + c4 * 4] = w;
      const int swc = 8 * (((row >> 3) + c4) & 7) + (row & 7);
      Vt[(4 * c4 + 0) * LDV + swc] = f2bf(pv[j].x);
      Vt[(4 * c4 + 1) * LDV + swc] = f2bf(pv[j].y);
      Vt[(4 * c4 + 2) * LDV + swc] = f2bf(pv[j].z);
      Vt[(4 * c4 + 3) * LDV + swc] = f2bf(pv[j].w);
    }
    __syncthreads();
    if (kt + 1 < N_KT) {
      const float4* kg = (const float4*)(k + hoff + (size_t)(kt + 1) * 64 * D_DIM);
      const float4* vg = (const float4*)(v + hoff + (size_t)(kt + 1) * 64 * D_DIM);
#pragma unroll
      for (int j = 0; j < 4; ++j) { pk[j] = kg[t + j * 256]; pv[j] = vg[t + j * 256]; }
    }
    int4 mq[2][4];
#pragma unroll
    for (int kb = 0; kb < 2; ++kb)
#pragma unroll
      for (int g = 0; g < 4; ++g)
        mq[kb][g] = *(const int4*)(mrow + kt * 64 + kb * 32 + g * 8 + hl * 4);
    f32x16 sT0 = zero16(), sT1 = zero16();
#pragma unroll
    for (int ks = 0; ks < 4; ++ks) {
      const bf16x8 aK0 = *(const bf16x8*)&Ks[col * LDK + ks * 16 + hl * 8];
      const bf16x8 aK1 = *(const bf16x8*)&Ks[(32 + col) * LDK + ks * 16 + hl * 8];
      sT0 = __builtin_amdgcn_mfma_f32_32x32x16_bf16(aK0, bQ[ks], sT0, 0, 0, 0);
      sT1 = __builtin_amdgcn_mfma_f32_32x32x16_bf16(aK1, bQ[ks], sT1, 0, 0, 0);
    }
    unsigned pw[2][8];
#pragma unroll
    for (int kb = 0; kb < 2; ++kb) {
      const f32x16 sT = kb ? sT1 : sT0;
      float e[16];
#pragma unroll
      for (int g = 0; g < 4; ++g) {
        const int4 mv = mq[kb][g];
        const int* mvp = &mv.x;
#pragma unroll
        for (int r3 = 0; r3 < 4; ++r3) {
          const int reg = g * 4 + r3;
          const float bias = mvp[r3] ? CM : 0.0f;
          const float ev = __builtin_amdgcn_exp2f(fmaf(sT[reg], C1, bias));
          e[reg] = ev;
          lacc += ev;
        }
        pw[kb][g * 2 + 0] = packbf(e[g * 4 + 0], e[g * 4 + 1]);
        pw[kb][g * 2 + 1] = packbf(e[g * 4 + 2], e[g * 4 + 3]);
      }
    }
#pragma unroll
    for (int ks = 0; ks < 4; ++ks) {
      const int kb = ks >> 1, h = ks & 1;
      const unsigned d0 = pw[kb][4 * h + 0], d1 = pw[kb][4 * h + 1];
      const unsigned d2 = pw[kb][4 * h + 2], d3 = pw[kb][4 * h + 3];
      const unsigned s0 = hl ? d0 : d2;
      const unsigned s1 = hl ? d1 : d3;
      const unsigned r0 = (unsigned)__shfl_xor((int)s0, 32);
      const unsigned r1 = (unsigned)__shfl_xor((int)s1, 32);
      union { bf16x8 v; unsigned d[4]; } pf;
      pf.d[0] = hl ? r0 : d0;
      pf.d[1] = hl ? r1 : d1;
      pf.d[2] = hl ? d2 : r0;
      pf.d[3] = hl ? d3 : r1;
      const int cpr = 8 * (((2 * ks + hl) + sw) & 7);
      const bf16x8 aV0 = *(const bf16x8*)&Vt[col * LDV + cpr];
      const bf16x8 aV1 = *(const bf16x8*)&Vt[(32 + col) * LDV + cpr];
      oT0 = __builtin_amdgcn_mfma_f32_32x32x16_bf16(aV0, pf.v, oT0, 0, 0, 0);
      oT1 = __builtin_amdgcn_mfma_f32_32x32x16_bf16(aV1, pf.v, oT1, 0, 0, 0);
    }
  }
  const float ltot = lacc + __shfl_xor(lacc, 32);
  const float inv = 1.0f / ltot;
  float* orow = out + hoff + (size_t)qg * D_DIM;
#pragma unroll
  for (int rg = 0; rg < 4; ++rg) {
    float4 w0, w1;
    w0.x = oT0[rg * 4 + 0] * inv; w0.y = oT0[rg * 4 + 1] * inv;
    w0.z = oT0[rg * 4 + 2] * inv; w0.w = oT0[rg * 4 + 3] * inv;
    w1.x = oT1[rg * 4 + 0] * inv; w1.y = oT1[rg * 4 + 1] * inv;
    w1.z = oT1[rg * 4 + 2] * inv; w1.w = oT1[rg * 4 + 3] * inv;
    *(float4*)(orow + 8 * rg + 4 * hl) = w0;
    *(float4*)(orow + 32 + 8 * rg + 4 * hl) = w1;
  }
}

extern "C" void kernel_launch(void* const* d_in, const int* in_sizes, int n_in,
                              void* d_out, int out_size, void* d_ws, size_t ws_size,
                              hipStream_t stream) {
  const float* q = (const float*)d_in[0];
  const float* k = (const float*)d_in[1];
  const float* v = (const float*)d_in[2];
  const int* mask = (const int*)d_in[3];
  float* out = (float*)d_out;

  const size_t kv_shorts = (size_t)NBH * N_KT * TILE_SHORTS;
  const size_t mw_words = (size_t)S_LEN * 2 * N_KT * 16;  // u32 count (8 MB)
  const size_t need = kv_shorts * sizeof(unsigned short) + mw_words * 4;

  if (ws_size >= need) {
    unsigned short* kvws = (unsigned short*)d_ws;
    u32* mwp = (u32*)(kvws + kv_shorts);
    prep_fused<<<dim3(N_KT * NBH + (S_LEN * 2 * N_KT * 4) / 256), dim3(256), 0,
                 stream>>>(k, v, mask, kvws, mwp);
    attn_fwd<<<dim3(S_LEN / 128, NBH), dim3(512), 0, stream>>>(q, kvws, mwp, out);
  } else {
    attn_fwd_self<<<dim3(S_LEN / 128, NBH), dim3(256), 0, stream>>>(q, k, v, mask, out);
  }
}